// Round 5
// baseline (428.773 us; speedup 1.0000x reference)
//
#include <hip/hip_runtime.h>
#include <hip/hip_bf16.h>

typedef __hip_bfloat16 bf16;
typedef __attribute__((ext_vector_type(8))) __bf16 bf16x8;
typedef __attribute__((ext_vector_type(4))) float f32x4;

#define SEQ 2048
#define HID 4096
#define NH 32
#define NKV 8
#define HD 128
#define KVDIM 1024
#define QKVN 6144

__device__ __forceinline__ void gl_lds16(const void* g, void* lds) {
  __builtin_amdgcn_global_load_lds((const __attribute__((address_space(1))) void*)g,
                                   (__attribute__((address_space(3))) void*)lds,
                                   16, 0, 0);
}

// pair-interleave permutation within a 128-wide head: h -> ((h&63)<<1)|(h>>6)
// After perm, gemm-col r holds original dim j+64e where j=(r&127)>>1, e=r&1.
__device__ __forceinline__ int perm127(int h) { return ((h & 63) << 1) | (h >> 6); }

// ---------------- elementwise fp32 -> bf16 ----------------
__global__ void cvt_kernel(const float* __restrict__ in, bf16* __restrict__ out, int n) {
  int i = (blockIdx.x * blockDim.x + threadIdx.x) * 4;
  if (i >= n) return;
  float4 v = *reinterpret_cast<const float4*>(in + i);
  bf16 o[4] = {__float2bfloat16(v.x), __float2bfloat16(v.y),
               __float2bfloat16(v.z), __float2bfloat16(v.w)};
  *reinterpret_cast<short4*>(out + i) = *reinterpret_cast<const short4*>(o);
}

// ---------------- bias concat [4096|1024|1024], Q/K regions pair-permuted ----------------
__global__ void concat_bias_kernel(const float* __restrict__ bq, const float* __restrict__ bk,
                                   const float* __restrict__ bv, float* __restrict__ o) {
  int i = blockIdx.x * blockDim.x + threadIdx.x;
  if (i >= QKVN) return;
  float v = (i < HID) ? bq[i] : (i < HID + KVDIM ? bk[i - HID] : bv[i - HID - KVDIM]);
  int oi = (i < HID + KVDIM) ? ((i & ~127) | perm127(i & 127)) : i;
  o[oi] = v;
}

// ---------------- tiled transpose fp32[R][C](stride si) -> bf16[C][R](stride so) ----------------
// perm!=0: output row (= original col) pair-permuted within each 128 block.
__global__ void transpose_cvt_kernel(const float* __restrict__ in, bf16* __restrict__ out,
                                     int si, int so, int perm) {
  __shared__ float tile[32][33];
  int c0 = blockIdx.x * 32, r0 = blockIdx.y * 32;
  int tx = threadIdx.x, ty = threadIdx.y;
#pragma unroll
  for (int i = 0; i < 32; i += 8)
    tile[ty + i][tx] = in[(size_t)(r0 + ty + i) * si + (c0 + tx)];
  __syncthreads();
#pragma unroll
  for (int i = 0; i < 32; i += 8) {
    int c = c0 + ty + i;
    int row = perm ? ((c & ~127) | perm127(c & 127)) : c;
    out[(size_t)row * so + (r0 + tx)] = __float2bfloat16(tile[tx][ty + i]);
  }
}

// ---------------- GEMM: 128x128 tile, BK=64, 4 waves ----------------
// mode 0: C = A*Bt^T (+bias), fp32 out to (bz ? C1 : C0), K-range offset bz*2048.
// mode 1: fused QKV epilogue: rope(Q,K) -> Qb/Kb bf16 (weights pair-permuted),
//         V -> Vt transposed bf16.
__global__ __launch_bounds__(256) void gemm_bt_kernel(
    const bf16* __restrict__ A, const bf16* __restrict__ Bt,
    const float* __restrict__ bias, float* __restrict__ C0, float* __restrict__ C1,
    bf16* __restrict__ Qb, bf16* __restrict__ Kb, bf16* __restrict__ Vt,
    int M, int N, int Ksub, int lda, int mode) {
  __shared__ bf16 As[128 * 64];
  __shared__ bf16 Bs[128 * 64];
  const int tid = threadIdx.x;
  const int lane = tid & 63;
  const int w = tid >> 6;
  const int wm = w >> 1, wn = w & 1;
  const int m0 = blockIdx.y * 128;
  const int n0 = blockIdx.x * 128;
  const int bz = blockIdx.z;
  const bf16* Ab = A + (size_t)bz * 2048;
  const bf16* Btb = Bt + (size_t)bz * 2048;
  float* Cb = bz ? C1 : C0;

  f32x4 acc[4][4];
  const f32x4 z = {0.f, 0.f, 0.f, 0.f};
#pragma unroll
  for (int i = 0; i < 4; i++)
#pragma unroll
    for (int j = 0; j < 4; j++) acc[i][j] = z;

  for (int kk = 0; kk < Ksub; kk += 64) {
#pragma unroll
    for (int it = 0; it < 4; ++it) {
      int c = w * 4 + it;
      int row = c * 8 + (lane >> 3);
      int sb = ((lane & 7) * 16) ^ ((row & 7) << 4);
      gl_lds16(Ab + (size_t)(m0 + row) * lda + kk + (sb >> 1), &As[c * 512]);
      gl_lds16(Btb + (size_t)(n0 + row) * lda + kk + (sb >> 1), &Bs[c * 512]);
    }
    __syncthreads();
#pragma unroll
    for (int ks = 0; ks < 64; ks += 32) {
      bf16x8 a[4], b[4];
#pragma unroll
      for (int mi = 0; mi < 4; ++mi) {
        int r = wm * 64 + mi * 16 + (lane & 15);
        int byt = r * 128 + (((ks + (lane >> 4) * 8) * 2) ^ ((r & 7) << 4));
        a[mi] = *reinterpret_cast<const bf16x8*>(reinterpret_cast<const char*>(As) + byt);
      }
#pragma unroll
      for (int ni = 0; ni < 4; ++ni) {
        int r = wn * 64 + ni * 16 + (lane & 15);
        int byt = r * 128 + (((ks + (lane >> 4) * 8) * 2) ^ ((r & 7) << 4));
        b[ni] = *reinterpret_cast<const bf16x8*>(reinterpret_cast<const char*>(Bs) + byt);
      }
#pragma unroll
      for (int mi = 0; mi < 4; ++mi)
#pragma unroll
        for (int ni = 0; ni < 4; ++ni)
          acc[mi][ni] = __builtin_amdgcn_mfma_f32_16x16x32_bf16(a[mi], b[ni], acc[mi][ni], 0, 0, 0);
    }
    __syncthreads();
  }

  if (mode == 0) {
#pragma unroll
    for (int ni = 0; ni < 4; ++ni) {
      int col = n0 + wn * 64 + ni * 16 + (lane & 15);
      float bv = bias ? bias[col] : 0.0f;
#pragma unroll
      for (int mi = 0; mi < 4; ++mi) {
        int rbase = m0 + wm * 64 + mi * 16 + (lane >> 4) * 4;
#pragma unroll
        for (int r = 0; r < 4; ++r)
          Cb[(size_t)(rbase + r) * N + col] = acc[mi][ni][r] + bv;
      }
    }
  } else {
    // fused QKV epilogue
#pragma unroll
    for (int ni = 0; ni < 4; ++ni) {
      int col = n0 + wn * 64 + ni * 16 + (lane & 15);
      float bv = bias[col];
      bool isV = (col >= HID + KVDIM);           // uniform per (wave, ni)
      int j = (col & 127) >> 1;
      int e = col & 1;
      float invf = __expf(-(float)j * 0.14391156831212787f);  // ln(10000)/64
#pragma unroll
      for (int mi = 0; mi < 4; ++mi) {
        int rbase = m0 + wm * 64 + mi * 16 + (lane >> 4) * 4;
        if (isV) {
          bf16 tmp[4];
#pragma unroll
          for (int r = 0; r < 4; ++r) tmp[r] = __float2bfloat16(acc[mi][ni][r] + bv);
          *reinterpret_cast<short4*>(Vt + (size_t)(col - HID - KVDIM) * SEQ + rbase) =
              *reinterpret_cast<const short4*>(tmp);
        } else {
#pragma unroll
          for (int r = 0; r < 4; ++r) {
            float v = acc[mi][ni][r] + bv;
            float p = __shfl_xor(v, 1);
            int row = rbase + r;
            float sn, cs;
            __sincosf((float)row * invf, &sn, &cs);
            float ov = e ? (v * cs + p * sn) : (v * cs - p * sn);
            int dout = j + (e ? 64 : 0);
            if (col < HID)
              Qb[(size_t)row * HID + (col & ~127) + dout] = __float2bfloat16(ov);
            else
              Kb[(size_t)row * KVDIM + ((col - HID) & ~127) + dout] = __float2bfloat16(ov);
          }
        }
      }
    }
  }
}

// ---------------- reduce: out = P0 + P1 ----------------
__global__ void reduce_kernel(const float* __restrict__ P0, const float* __restrict__ P1,
                              float* __restrict__ out, int n) {
  int i = (blockIdx.x * blockDim.x + threadIdx.x) * 4;
  if (i >= n) return;
  float4 a = *reinterpret_cast<const float4*>(P0 + i);
  float4 b = *reinterpret_cast<const float4*>(P1 + i);
  float4 o = {a.x + b.x, a.y + b.y, a.z + b.z, a.w + b.w};
  *reinterpret_cast<float4*>(out + i) = o;
}

// ---------------- flash attention with KV-split load balancing ----------------
__global__ __launch_bounds__(256) void attn_kernel(
    const bf16* __restrict__ Q,   // [SEQ][HID]
    const bf16* __restrict__ Kb,  // [SEQ][KVDIM]
    const bf16* __restrict__ Vt,  // [KVDIM][SEQ]
    bf16* __restrict__ AO,        // [SEQ][HID]
    float* __restrict__ Opart,    // [2][NH][1024][HD]
    float* __restrict__ Ml) {     // [2][NH][1024][2]
  __shared__ bf16 Ks[64 * 128];
  __shared__ bf16 Vs[128 * 64];
  __shared__ bf16 Ps[4][16 * 64];
  const int tid = threadIdx.x, lane = tid & 63, w = tid >> 6;
  const int b = blockIdx.x;
  const int H = b & 31;
  const int tt = b >> 5;
  int qb, lo, hi, half;
  bool split;
  if (tt < 32) {
    qb = 16 + ((31 - tt) >> 1);
    half = tt & 1;
    int n = qb + 1, mid = n >> 1;
    lo = half ? mid : 0;
    hi = half ? n : mid;
    split = true;
  } else {
    qb = 47 - tt;
    half = 0;
    lo = 0;
    hi = qb + 1;
    split = false;
  }
  const int kvh = H >> 2;
  const int qw = qb * 64 + w * 16;

  bf16x8 aq[4];
#pragma unroll
  for (int kd = 0; kd < 4; ++kd) {
    int row = qw + (lane & 15);
    int d = kd * 32 + (lane >> 4) * 8;
    aq[kd] = *reinterpret_cast<const bf16x8*>(Q + (size_t)row * HID + H * HD + d);
  }

  float m_run[4], l_run[4];
  f32x4 o[8];
  const f32x4 z = {0.f, 0.f, 0.f, 0.f};
#pragma unroll
  for (int r = 0; r < 4; ++r) { m_run[r] = -1e30f; l_run[r] = 0.0f; }
#pragma unroll
  for (int dt = 0; dt < 8; ++dt) o[dt] = z;

  const float scale = 0.08838834764831845f;

  for (int t = lo; t < hi; ++t) {
    int kvbase = t * 64;
#pragma unroll
    for (int it = 0; it < 4; ++it) {
      int c = w * 4 + it;
      int row = c * 4 + (lane >> 4);
      int sb = ((lane & 15) * 16) ^ ((row & 7) << 4);
      gl_lds16(Kb + (size_t)(kvbase + row) * KVDIM + kvh * HD + (sb >> 1), &Ks[c * 512]);
    }
#pragma unroll
    for (int it = 0; it < 4; ++it) {
      int c = w * 4 + it;
      int row = c * 8 + (lane >> 3);
      int sb = ((lane & 7) * 16) ^ ((row & 7) << 4);
      gl_lds16(Vt + (size_t)(kvh * HD + row) * SEQ + kvbase + (sb >> 1), &Vs[c * 512]);
    }
    __syncthreads();

    f32x4 sf[4];
#pragma unroll
    for (int j = 0; j < 4; ++j) sf[j] = z;
#pragma unroll
    for (int j = 0; j < 4; ++j) {
#pragma unroll
      for (int kd = 0; kd < 4; ++kd) {
        int r = j * 16 + (lane & 15);
        int byt = r * 256 + (((kd * 32 + (lane >> 4) * 8) * 2) ^ ((r & 7) << 4));
        bf16x8 bfr = *reinterpret_cast<const bf16x8*>(reinterpret_cast<const char*>(Ks) + byt);
        sf[j] = __builtin_amdgcn_mfma_f32_16x16x32_bf16(aq[kd], bfr, sf[j], 0, 0, 0);
      }
    }

    float vals[4][4];
    bool diag = (t == qb);
#pragma unroll
    for (int j = 0; j < 4; ++j)
#pragma unroll
      for (int r = 0; r < 4; ++r) {
        float v = sf[j][r] * scale;
        if (diag) {
          int qa = qw + (lane >> 4) * 4 + r;
          int ka = kvbase + j * 16 + (lane & 15);
          if (ka > qa) v = -1e30f;
        }
        vals[j][r] = v;
      }

    float mt[4], alpha[4];
#pragma unroll
    for (int r = 0; r < 4; ++r) {
      float m = fmaxf(fmaxf(vals[0][r], vals[1][r]), fmaxf(vals[2][r], vals[3][r]));
#pragma unroll
      for (int sh = 8; sh >= 1; sh >>= 1) m = fmaxf(m, __shfl_xor(m, sh, 16));
      float mn = fmaxf(m_run[r], m);
      alpha[r] = __expf(m_run[r] - mn);
      m_run[r] = mn;
      mt[r] = mn;
    }

    float rs[4] = {0.f, 0.f, 0.f, 0.f};
#pragma unroll
    for (int j = 0; j < 4; ++j)
#pragma unroll
      for (int r = 0; r < 4; ++r) {
        float p = __expf(vals[j][r] - mt[r]);
        rs[r] += p;
        int prow = (lane >> 4) * 4 + r;
        int pcol = j * 16 + (lane & 15);
        int byt = prow * 128 + ((pcol * 2) ^ ((prow & 7) << 4));
        *reinterpret_cast<bf16*>(reinterpret_cast<char*>(&Ps[w][0]) + byt) = __float2bfloat16(p);
      }
#pragma unroll
    for (int r = 0; r < 4; ++r) {
#pragma unroll
      for (int sh = 8; sh >= 1; sh >>= 1) rs[r] += __shfl_xor(rs[r], sh, 16);
      l_run[r] = l_run[r] * alpha[r] + rs[r];
    }
#pragma unroll
    for (int dt = 0; dt < 8; ++dt)
#pragma unroll
      for (int r = 0; r < 4; ++r) o[dt][r] *= alpha[r];

    bf16x8 pa[2];
#pragma unroll
    for (int ks = 0; ks < 2; ++ks) {
      int prow = lane & 15;
      int byt = prow * 128 + (((ks * 32 + (lane >> 4) * 8) * 2) ^ ((prow & 7) << 4));
      pa[ks] = *reinterpret_cast<const bf16x8*>(reinterpret_cast<const char*>(&Ps[w][0]) + byt);
    }
#pragma unroll
    for (int dt = 0; dt < 8; ++dt)
#pragma unroll
      for (int ks = 0; ks < 2; ++ks) {
        int vrow = dt * 16 + (lane & 15);
        int byt = vrow * 128 + (((ks * 32 + (lane >> 4) * 8) * 2) ^ ((vrow & 7) << 4));
        bf16x8 vb = *reinterpret_cast<const bf16x8*>(reinterpret_cast<const char*>(Vs) + byt);
        o[dt] = __builtin_amdgcn_mfma_f32_16x16x32_bf16(pa[ks], vb, o[dt], 0, 0, 0);
      }
    __syncthreads();
  }

  if (!split) {
#pragma unroll
    for (int dt = 0; dt < 8; ++dt)
#pragma unroll
      for (int r = 0; r < 4; ++r) {
        int qa = qw + (lane >> 4) * 4 + r;
        int d = dt * 16 + (lane & 15);
        AO[(size_t)qa * HID + H * HD + d] = __float2bfloat16(o[dt][r] / l_run[r]);
      }
  } else {
    size_t pbase = ((size_t)(half * NH + H) * 1024);
#pragma unroll
    for (int dt = 0; dt < 8; ++dt)
#pragma unroll
      for (int r = 0; r < 4; ++r) {
        int qa = qw + (lane >> 4) * 4 + r;
        int d = dt * 16 + (lane & 15);
        Opart[(pbase + (qa - 1024)) * HD + d] = o[dt][r];
      }
    if ((lane & 15) == 0) {
#pragma unroll
      for (int r = 0; r < 4; ++r) {
        int qa = qw + (lane >> 4) * 4 + r;
        Ml[(pbase + (qa - 1024)) * 2 + 0] = m_run[r];
        Ml[(pbase + (qa - 1024)) * 2 + 1] = l_run[r];
      }
    }
  }
}

// ---------------- merge split-attention partials ----------------
__global__ __launch_bounds__(256) void merge_kernel(
    const float* __restrict__ Opart, const float* __restrict__ Ml,
    bf16* __restrict__ AO) {
  int i = blockIdx.x * 256 + threadIdx.x;
  int dq = (i & 31) << 2;
  int row = (i >> 5) & 1023;
  int H = i >> 15;
  size_t b1 = (size_t)H * 1024 + row;
  size_t b2 = (size_t)(NH + H) * 1024 + row;
  float m1 = Ml[b1 * 2], l1 = Ml[b1 * 2 + 1];
  float m2 = Ml[b2 * 2], l2 = Ml[b2 * 2 + 1];
  float M = fmaxf(m1, m2);
  float w1 = __expf(m1 - M), w2 = __expf(m2 - M);
  float inv = 1.0f / (l1 * w1 + l2 * w2);
  float4 o1 = *reinterpret_cast<const float4*>(Opart + b1 * HD + dq);
  float4 o2 = *reinterpret_cast<const float4*>(Opart + b2 * HD + dq);
  bf16 o[4] = {__float2bfloat16((o1.x * w1 + o2.x * w2) * inv),
               __float2bfloat16((o1.y * w1 + o2.y * w2) * inv),
               __float2bfloat16((o1.z * w1 + o2.z * w2) * inv),
               __float2bfloat16((o1.w * w1 + o2.w * w2) * inv)};
  *reinterpret_cast<short4*>(AO + (size_t)(1024 + row) * HID + H * HD + dq) =
      *reinterpret_cast<const short4*>(o);
}

extern "C" void kernel_launch(void* const* d_in, const int* in_sizes, int n_in,
                              void* d_out, int out_size, void* d_ws, size_t ws_size,
                              hipStream_t stream) {
  const float* hidden = (const float*)d_in[0];
  const float* Wq = (const float*)d_in[2];
  const float* bq = (const float*)d_in[3];
  const float* Wk = (const float*)d_in[4];
  const float* bk = (const float*)d_in[5];
  const float* Wv = (const float*)d_in[6];
  const float* bv = (const float*)d_in[7];
  const float* Wo = (const float*)d_in[8];
  float* out = (float*)d_out;

  char* w = (char*)d_ws;
  bf16* Wqkvt = (bf16*)w; w += (size_t)QKVN * HID * 2;   // [0,48M)  rows: [Qp|Kp|V]
  bf16* Xb    = (bf16*)w; w += (size_t)SEQ * HID * 2;    // [48,64M)
  bf16* Qb    = (bf16*)w; w += (size_t)SEQ * HID * 2;    // [64,80M)
  bf16* Kb    = (bf16*)w; w += (size_t)SEQ * KVDIM * 2;  // [80,84M)
  bf16* Vt    = (bf16*)w; w += (size_t)KVDIM * SEQ * 2;  // [84,88M)
  bf16* Wot   = (bf16*)w; w += (size_t)HID * HID * 2;    // [88,120M)
  float* bqkv = (float*)w; w += (size_t)QKVN * 4;
  bf16* AO    = (bf16*)w; w += (size_t)SEQ * HID * 2;
  // aliases (sequenced):
  float* Opart = (float*)Wqkvt;                           // 32M, after QKV GEMM
  float* Ml    = (float*)((char*)Wqkvt + (size_t)32 * 1024 * 1024);  // 0.5M
  float* P0    = (float*)Wqkvt;                           // 32M, after merge
  float* P1    = (float*)Xb;                              // 32M (Xb+Qb), after attn

  cvt_kernel<<<(SEQ * HID) / 1024, 256, 0, stream>>>(hidden, Xb, SEQ * HID);
  concat_bias_kernel<<<QKVN / 256, 256, 0, stream>>>(bq, bk, bv, bqkv);
  transpose_cvt_kernel<<<dim3(HID / 32, HID / 32), dim3(32, 8), 0, stream>>>(
      Wq, Wqkvt, HID, HID, 1);
  transpose_cvt_kernel<<<dim3(KVDIM / 32, HID / 32), dim3(32, 8), 0, stream>>>(
      Wk, Wqkvt + (size_t)HID * HID, KVDIM, HID, 1);
  transpose_cvt_kernel<<<dim3(KVDIM / 32, HID / 32), dim3(32, 8), 0, stream>>>(
      Wv, Wqkvt + (size_t)(HID + KVDIM) * HID, KVDIM, HID, 0);
  transpose_cvt_kernel<<<dim3(HID / 32, HID / 32), dim3(32, 8), 0, stream>>>(
      Wo, Wot, HID, HID, 0);

  // fused QKV GEMM: rope->Qb/Kb, V->Vt (transposed), weights pair-permuted
  gemm_bt_kernel<<<dim3(QKVN / 128, SEQ / 128, 1), 256, 0, stream>>>(
      Xb, Wqkvt, bqkv, nullptr, nullptr, Qb, Kb, Vt, SEQ, QKVN, HID, HID, 1);

  attn_kernel<<<1536, 256, 0, stream>>>(Qb, Kb, Vt, AO, Opart, Ml);
  merge_kernel<<<(NH * 1024 * 32) / 256, 256, 0, stream>>>(Opart, Ml, AO);

  // Wo GEMM, split-K=2 (blockIdx.z), partials P0/P1, then reduce
  gemm_bt_kernel<<<dim3(HID / 128, SEQ / 128, 2), 256, 0, stream>>>(
      AO, Wot, nullptr, P0, P1, nullptr, nullptr, nullptr, SEQ, HID, 2048, HID, 0);
  reduce_kernel<<<(SEQ * HID) / 1024, 256, 0, stream>>>(P0, P1, out, SEQ * HID);
}

// Round 6
// 421.600 us; speedup vs baseline: 1.0170x; 1.0170x over previous
//
#include <hip/hip_runtime.h>
#include <hip/hip_bf16.h>

typedef __hip_bfloat16 bf16;
typedef __attribute__((ext_vector_type(8))) __bf16 bf16x8;
typedef __attribute__((ext_vector_type(4))) float f32x4;

#define SEQ 2048
#define HID 4096
#define NH 32
#define NKV 8
#define HD 128
#define KVDIM 1024
#define QKVN 6144

__device__ __forceinline__ void gl_lds16(const void* g, void* lds) {
  __builtin_amdgcn_global_load_lds((const __attribute__((address_space(1))) void*)g,
                                   (__attribute__((address_space(3))) void*)lds,
                                   16, 0, 0);
}

// ---------------- elementwise fp32 -> bf16 ----------------
__global__ void cvt_kernel(const float* __restrict__ in, bf16* __restrict__ out, int n) {
  int i = (blockIdx.x * blockDim.x + threadIdx.x) * 4;
  if (i >= n) return;
  float4 v = *reinterpret_cast<const float4*>(in + i);
  bf16 o[4] = {__float2bfloat16(v.x), __float2bfloat16(v.y),
               __float2bfloat16(v.z), __float2bfloat16(v.w)};
  *reinterpret_cast<short4*>(out + i) = *reinterpret_cast<const short4*>(o);
}

// ---------------- bias concat [4096|1024|1024] ----------------
__global__ void concat_bias_kernel(const float* __restrict__ bq, const float* __restrict__ bk,
                                   const float* __restrict__ bv, float* __restrict__ o) {
  int i = blockIdx.x * blockDim.x + threadIdx.x;
  if (i >= QKVN) return;
  o[i] = (i < HID) ? bq[i] : (i < HID + KVDIM ? bk[i - HID] : bv[i - HID - KVDIM]);
}

// ---------------- tiled transpose fp32[R][C](stride si) -> bf16[C][R](stride so) ----------------
__global__ void transpose_cvt_kernel(const float* __restrict__ in, bf16* __restrict__ out,
                                     int si, int so) {
  __shared__ float tile[32][33];
  int c0 = blockIdx.x * 32, r0 = blockIdx.y * 32;
  int tx = threadIdx.x, ty = threadIdx.y;
#pragma unroll
  for (int i = 0; i < 32; i += 8)
    tile[ty + i][tx] = in[(size_t)(r0 + ty + i) * si + (c0 + tx)];
  __syncthreads();
#pragma unroll
  for (int i = 0; i < 32; i += 8)
    out[(size_t)(c0 + ty + i) * so + (r0 + tx)] = __float2bfloat16(tile[tx][ty + i]);
}

// ---------------- GEMM: 128x128 tile, BK=64, 4 waves ----------------
// Wave col mapping: col = n0 + wn*16 + ni*32 + (lane&15)  -> RoPE partner
// (d, d+64) is (ni, ni+2) in the SAME thread.
// mode 0: C = A*Bt^T (+bias), fp32 out to (bz ? C1 : C0), K offset bz*2048.
// mode 1: fused QKV epilogue: rope(Q,K)->Qb/Kb bf16, V->Vt transposed bf16.
__global__ __launch_bounds__(256) void gemm_bt_kernel(
    const bf16* __restrict__ A, const bf16* __restrict__ Bt,
    const float* __restrict__ bias, float* __restrict__ C0, float* __restrict__ C1,
    bf16* __restrict__ Qb, bf16* __restrict__ Kb, bf16* __restrict__ Vt,
    int M, int N, int Ksub, int lda, int mode) {
  __shared__ bf16 As[128 * 64];
  __shared__ bf16 Bs[128 * 64];
  const int tid = threadIdx.x;
  const int lane = tid & 63;
  const int w = tid >> 6;
  const int wm = w >> 1, wn = w & 1;
  const int m0 = blockIdx.y * 128;
  const int n0 = blockIdx.x * 128;
  const int bz = blockIdx.z;
  const bf16* Ab = A + (size_t)bz * 2048;
  const bf16* Btb = Bt + (size_t)bz * 2048;
  float* Cb = bz ? C1 : C0;

  f32x4 acc[4][4];
  const f32x4 z = {0.f, 0.f, 0.f, 0.f};
#pragma unroll
  for (int i = 0; i < 4; i++)
#pragma unroll
    for (int j = 0; j < 4; j++) acc[i][j] = z;

  for (int kk = 0; kk < Ksub; kk += 64) {
#pragma unroll
    for (int it = 0; it < 4; ++it) {
      int c = w * 4 + it;
      int row = c * 8 + (lane >> 3);
      int sb = ((lane & 7) * 16) ^ ((row & 7) << 4);
      gl_lds16(Ab + (size_t)(m0 + row) * lda + kk + (sb >> 1), &As[c * 512]);
      gl_lds16(Btb + (size_t)(n0 + row) * lda + kk + (sb >> 1), &Bs[c * 512]);
    }
    __syncthreads();
#pragma unroll
    for (int ks = 0; ks < 64; ks += 32) {
      bf16x8 a[4], b[4];
#pragma unroll
      for (int mi = 0; mi < 4; ++mi) {
        int r = wm * 64 + mi * 16 + (lane & 15);
        int byt = r * 128 + (((ks + (lane >> 4) * 8) * 2) ^ ((r & 7) << 4));
        a[mi] = *reinterpret_cast<const bf16x8*>(reinterpret_cast<const char*>(As) + byt);
      }
#pragma unroll
      for (int ni = 0; ni < 4; ++ni) {
        int r = wn * 16 + ni * 32 + (lane & 15);
        int byt = r * 128 + (((ks + (lane >> 4) * 8) * 2) ^ ((r & 7) << 4));
        b[ni] = *reinterpret_cast<const bf16x8*>(reinterpret_cast<const char*>(Bs) + byt);
      }
#pragma unroll
      for (int mi = 0; mi < 4; ++mi)
#pragma unroll
        for (int ni = 0; ni < 4; ++ni)
          acc[mi][ni] = __builtin_amdgcn_mfma_f32_16x16x32_bf16(a[mi], b[ni], acc[mi][ni], 0, 0, 0);
    }
    __syncthreads();
  }

  if (mode == 0) {
#pragma unroll
    for (int ni = 0; ni < 4; ++ni) {
      int col = n0 + wn * 16 + ni * 32 + (lane & 15);
      float bv = bias ? bias[col] : 0.0f;
#pragma unroll
      for (int mi = 0; mi < 4; ++mi) {
        int rbase = m0 + wm * 64 + mi * 16 + (lane >> 4) * 4;
#pragma unroll
        for (int r = 0; r < 4; ++r)
          Cb[(size_t)(rbase + r) * N + col] = acc[mi][ni][r] + bv;
      }
    }
  } else if (n0 >= HID + KVDIM) {
    // V epilogue: transposed bf16 store
#pragma unroll
    for (int ni = 0; ni < 4; ++ni) {
      int col = n0 + wn * 16 + ni * 32 + (lane & 15);
      float bv = bias[col];
      int vcol = col - (HID + KVDIM);
#pragma unroll
      for (int mi = 0; mi < 4; ++mi) {
        int rbase = m0 + wm * 64 + mi * 16 + (lane >> 4) * 4;
        bf16 tmp[4];
#pragma unroll
        for (int r = 0; r < 4; ++r) tmp[r] = __float2bfloat16(acc[mi][ni][r] + bv);
        *reinterpret_cast<short4*>(Vt + (size_t)vcol * SEQ + rbase) =
            *reinterpret_cast<const short4*>(tmp);
      }
    }
  } else {
    // Q/K rope epilogue: partner (d, d+64) = (acc[*][ni], acc[*][ni+2])
    bf16* Ob;
    int cb, ostr;
    if (n0 < HID) { Ob = Qb; cb = n0; ostr = HID; }
    else { Ob = Kb; cb = n0 - HID; ostr = KVDIM; }
#pragma unroll
    for (int ni = 0; ni < 2; ++ni) {
      int d = wn * 16 + ni * 32 + (lane & 15);     // 0..63
      float bv1 = bias[n0 + d];
      float bv2 = bias[n0 + d + 64];
      float invf = __expf(-(float)d * 0.14391156831212787f);  // ln(10000)/64
#pragma unroll
      for (int mi = 0; mi < 4; ++mi) {
        int rbase = m0 + wm * 64 + mi * 16 + (lane >> 4) * 4;
#pragma unroll
        for (int r = 0; r < 4; ++r) {
          int row = rbase + r;
          float sn, cs;
          __sincosf((float)row * invf, &sn, &cs);
          float x1 = acc[mi][ni][r] + bv1;
          float x2 = acc[mi][ni + 2][r] + bv2;
          Ob[(size_t)row * ostr + cb + d]      = __float2bfloat16(x1 * cs - x2 * sn);
          Ob[(size_t)row * ostr + cb + d + 64] = __float2bfloat16(x2 * cs + x1 * sn);
        }
      }
    }
  }
}

// ---------------- reduce: out = P0 + P1 ----------------
__global__ void reduce_kernel(const float* __restrict__ P0, const float* __restrict__ P1,
                              float* __restrict__ out, int n) {
  int i = (blockIdx.x * blockDim.x + threadIdx.x) * 4;
  if (i >= n) return;
  float4 a = *reinterpret_cast<const float4*>(P0 + i);
  float4 b = *reinterpret_cast<const float4*>(P1 + i);
  float4 o = {a.x + b.x, a.y + b.y, a.z + b.z, a.w + b.w};
  *reinterpret_cast<float4*>(out + i) = o;
}

// ---------------- flash attention with KV-split load balancing ----------------
__global__ __launch_bounds__(256) void attn_kernel(
    const bf16* __restrict__ Q,   // [SEQ][HID]
    const bf16* __restrict__ Kb,  // [SEQ][KVDIM]
    const bf16* __restrict__ Vt,  // [KVDIM][SEQ]
    bf16* __restrict__ AO,        // [SEQ][HID]
    float* __restrict__ Opart,    // [2][NH][1024][HD]
    float* __restrict__ Ml) {     // [2][NH][1024][2]
  __shared__ bf16 Ks[64 * 128];
  __shared__ bf16 Vs[128 * 64];
  __shared__ bf16 Ps[4][16 * 64];
  const int tid = threadIdx.x, lane = tid & 63, w = tid >> 6;
  const int b = blockIdx.x;
  const int H = b & 31;
  const int tt = b >> 5;
  int qb, lo, hi, half;
  bool split;
  if (tt < 32) {
    qb = 16 + ((31 - tt) >> 1);
    half = tt & 1;
    int n = qb + 1, mid = n >> 1;
    lo = half ? mid : 0;
    hi = half ? n : mid;
    split = true;
  } else {
    qb = 47 - tt;
    half = 0;
    lo = 0;
    hi = qb + 1;
    split = false;
  }
  const int kvh = H >> 2;
  const int qw = qb * 64 + w * 16;

  bf16x8 aq[4];
#pragma unroll
  for (int kd = 0; kd < 4; ++kd) {
    int row = qw + (lane & 15);
    int d = kd * 32 + (lane >> 4) * 8;
    aq[kd] = *reinterpret_cast<const bf16x8*>(Q + (size_t)row * HID + H * HD + d);
  }

  float m_run[4], l_run[4];
  f32x4 o[8];
  const f32x4 z = {0.f, 0.f, 0.f, 0.f};
#pragma unroll
  for (int r = 0; r < 4; ++r) { m_run[r] = -1e30f; l_run[r] = 0.0f; }
#pragma unroll
  for (int dt = 0; dt < 8; ++dt) o[dt] = z;

  const float scale = 0.08838834764831845f;

  for (int t = lo; t < hi; ++t) {
    int kvbase = t * 64;
#pragma unroll
    for (int it = 0; it < 4; ++it) {
      int c = w * 4 + it;
      int row = c * 4 + (lane >> 4);
      int sb = ((lane & 15) * 16) ^ ((row & 7) << 4);
      gl_lds16(Kb + (size_t)(kvbase + row) * KVDIM + kvh * HD + (sb >> 1), &Ks[c * 512]);
    }
#pragma unroll
    for (int it = 0; it < 4; ++it) {
      int c = w * 4 + it;
      int row = c * 8 + (lane >> 3);
      int sb = ((lane & 7) * 16) ^ ((row & 7) << 4);
      gl_lds16(Vt + (size_t)(kvh * HD + row) * SEQ + kvbase + (sb >> 1), &Vs[c * 512]);
    }
    __syncthreads();

    f32x4 sf[4];
#pragma unroll
    for (int j = 0; j < 4; ++j) sf[j] = z;
#pragma unroll
    for (int j = 0; j < 4; ++j) {
#pragma unroll
      for (int kd = 0; kd < 4; ++kd) {
        int r = j * 16 + (lane & 15);
        int byt = r * 256 + (((kd * 32 + (lane >> 4) * 8) * 2) ^ ((r & 7) << 4));
        bf16x8 bfr = *reinterpret_cast<const bf16x8*>(reinterpret_cast<const char*>(Ks) + byt);
        sf[j] = __builtin_amdgcn_mfma_f32_16x16x32_bf16(aq[kd], bfr, sf[j], 0, 0, 0);
      }
    }

    float vals[4][4];
    bool diag = (t == qb);
#pragma unroll
    for (int j = 0; j < 4; ++j)
#pragma unroll
      for (int r = 0; r < 4; ++r) {
        float v = sf[j][r] * scale;
        if (diag) {
          int qa = qw + (lane >> 4) * 4 + r;
          int ka = kvbase + j * 16 + (lane & 15);
          if (ka > qa) v = -1e30f;
        }
        vals[j][r] = v;
      }

    float mt[4], alpha[4];
#pragma unroll
    for (int r = 0; r < 4; ++r) {
      float m = fmaxf(fmaxf(vals[0][r], vals[1][r]), fmaxf(vals[2][r], vals[3][r]));
#pragma unroll
      for (int sh = 8; sh >= 1; sh >>= 1) m = fmaxf(m, __shfl_xor(m, sh, 16));
      float mn = fmaxf(m_run[r], m);
      alpha[r] = __expf(m_run[r] - mn);
      m_run[r] = mn;
      mt[r] = mn;
    }

    float rs[4] = {0.f, 0.f, 0.f, 0.f};
#pragma unroll
    for (int j = 0; j < 4; ++j)
#pragma unroll
      for (int r = 0; r < 4; ++r) {
        float p = __expf(vals[j][r] - mt[r]);
        rs[r] += p;
        int prow = (lane >> 4) * 4 + r;
        int pcol = j * 16 + (lane & 15);
        int byt = prow * 128 + ((pcol * 2) ^ ((prow & 7) << 4));
        *reinterpret_cast<bf16*>(reinterpret_cast<char*>(&Ps[w][0]) + byt) = __float2bfloat16(p);
      }
#pragma unroll
    for (int r = 0; r < 4; ++r) {
#pragma unroll
      for (int sh = 8; sh >= 1; sh >>= 1) rs[r] += __shfl_xor(rs[r], sh, 16);
      l_run[r] = l_run[r] * alpha[r] + rs[r];
    }
#pragma unroll
    for (int dt = 0; dt < 8; ++dt)
#pragma unroll
      for (int r = 0; r < 4; ++r) o[dt][r] *= alpha[r];

    bf16x8 pa[2];
#pragma unroll
    for (int ks = 0; ks < 2; ++ks) {
      int prow = lane & 15;
      int byt = prow * 128 + (((ks * 32 + (lane >> 4) * 8) * 2) ^ ((prow & 7) << 4));
      pa[ks] = *reinterpret_cast<const bf16x8*>(reinterpret_cast<const char*>(&Ps[w][0]) + byt);
    }
#pragma unroll
    for (int dt = 0; dt < 8; ++dt)
#pragma unroll
      for (int ks = 0; ks < 2; ++ks) {
        int vrow = dt * 16 + (lane & 15);
        int byt = vrow * 128 + (((ks * 32 + (lane >> 4) * 8) * 2) ^ ((vrow & 7) << 4));
        bf16x8 vb = *reinterpret_cast<const bf16x8*>(reinterpret_cast<const char*>(Vs) + byt);
        o[dt] = __builtin_amdgcn_mfma_f32_16x16x32_bf16(pa[ks], vb, o[dt], 0, 0, 0);
      }
    __syncthreads();
  }

  if (!split) {
#pragma unroll
    for (int dt = 0; dt < 8; ++dt)
#pragma unroll
      for (int r = 0; r < 4; ++r) {
        int qa = qw + (lane >> 4) * 4 + r;
        int d = dt * 16 + (lane & 15);
        AO[(size_t)qa * HID + H * HD + d] = __float2bfloat16(o[dt][r] / l_run[r]);
      }
  } else {
    size_t pbase = ((size_t)(half * NH + H) * 1024);
#pragma unroll
    for (int dt = 0; dt < 8; ++dt)
#pragma unroll
      for (int r = 0; r < 4; ++r) {
        int qa = qw + (lane >> 4) * 4 + r;
        int d = dt * 16 + (lane & 15);
        Opart[(pbase + (qa - 1024)) * HD + d] = o[dt][r];
      }
    if ((lane & 15) == 0) {
#pragma unroll
      for (int r = 0; r < 4; ++r) {
        int qa = qw + (lane >> 4) * 4 + r;
        Ml[(pbase + (qa - 1024)) * 2 + 0] = m_run[r];
        Ml[(pbase + (qa - 1024)) * 2 + 1] = l_run[r];
      }
    }
  }
}

// ---------------- merge split-attention partials ----------------
__global__ __launch_bounds__(256) void merge_kernel(
    const float* __restrict__ Opart, const float* __restrict__ Ml,
    bf16* __restrict__ AO) {
  int i = blockIdx.x * 256 + threadIdx.x;
  int dq = (i & 31) << 2;
  int row = (i >> 5) & 1023;
  int H = i >> 15;
  size_t b1 = (size_t)H * 1024 + row;
  size_t b2 = (size_t)(NH + H) * 1024 + row;
  float m1 = Ml[b1 * 2], l1 = Ml[b1 * 2 + 1];
  float m2 = Ml[b2 * 2], l2 = Ml[b2 * 2 + 1];
  float M = fmaxf(m1, m2);
  float w1 = __expf(m1 - M), w2 = __expf(m2 - M);
  float inv = 1.0f / (l1 * w1 + l2 * w2);
  float4 o1 = *reinterpret_cast<const float4*>(Opart + b1 * HD + dq);
  float4 o2 = *reinterpret_cast<const float4*>(Opart + b2 * HD + dq);
  bf16 o[4] = {__float2bfloat16((o1.x * w1 + o2.x * w2) * inv),
               __float2bfloat16((o1.y * w1 + o2.y * w2) * inv),
               __float2bfloat16((o1.z * w1 + o2.z * w2) * inv),
               __float2bfloat16((o1.w * w1 + o2.w * w2) * inv)};
  *reinterpret_cast<short4*>(AO + (size_t)(1024 + row) * HID + H * HD + dq) =
      *reinterpret_cast<const short4*>(o);
}

extern "C" void kernel_launch(void* const* d_in, const int* in_sizes, int n_in,
                              void* d_out, int out_size, void* d_ws, size_t ws_size,
                              hipStream_t stream) {
  const float* hidden = (const float*)d_in[0];
  const float* Wq = (const float*)d_in[2];
  const float* bq = (const float*)d_in[3];
  const float* Wk = (const float*)d_in[4];
  const float* bk = (const float*)d_in[5];
  const float* Wv = (const float*)d_in[6];
  const float* bv = (const float*)d_in[7];
  const float* Wo = (const float*)d_in[8];
  float* out = (float*)d_out;

  char* w = (char*)d_ws;
  bf16* Wqkvt = (bf16*)w; w += (size_t)QKVN * HID * 2;   // [0,48M)  rows: [Q|K|V]
  bf16* Xb    = (bf16*)w; w += (size_t)SEQ * HID * 2;    // [48,64M)
  bf16* Qb    = (bf16*)w; w += (size_t)SEQ * HID * 2;    // [64,80M)
  bf16* Kb    = (bf16*)w; w += (size_t)SEQ * KVDIM * 2;  // [80,84M)
  bf16* Vt    = (bf16*)w; w += (size_t)KVDIM * SEQ * 2;  // [84,88M)
  bf16* Wot   = (bf16*)w; w += (size_t)HID * HID * 2;    // [88,120M)
  float* bqkv = (float*)w; w += (size_t)QKVN * 4;
  bf16* AO    = (bf16*)w; w += (size_t)SEQ * HID * 2;
  // aliases (sequenced):
  float* Opart = (float*)Wqkvt;                           // 32M, after QKV GEMM
  float* Ml    = (float*)((char*)Wqkvt + (size_t)32 * 1024 * 1024);  // 0.5M
  float* P0    = (float*)Wqkvt;                           // 32M, after merge
  float* P1    = (float*)Xb;                              // 32M (Xb+Qb), after attn

  cvt_kernel<<<(SEQ * HID) / 1024, 256, 0, stream>>>(hidden, Xb, SEQ * HID);
  concat_bias_kernel<<<QKVN / 256, 256, 0, stream>>>(bq, bk, bv, bqkv);
  transpose_cvt_kernel<<<dim3(HID / 32, HID / 32), dim3(32, 8), 0, stream>>>(
      Wq, Wqkvt, HID, HID);
  transpose_cvt_kernel<<<dim3(KVDIM / 32, HID / 32), dim3(32, 8), 0, stream>>>(
      Wk, Wqkvt + (size_t)HID * HID, KVDIM, HID);
  transpose_cvt_kernel<<<dim3(KVDIM / 32, HID / 32), dim3(32, 8), 0, stream>>>(
      Wv, Wqkvt + (size_t)(HID + KVDIM) * HID, KVDIM, HID);
  transpose_cvt_kernel<<<dim3(HID / 32, HID / 32), dim3(32, 8), 0, stream>>>(
      Wo, Wot, HID, HID);

  // fused QKV GEMM: rope->Qb/Kb, V->Vt (transposed)
  gemm_bt_kernel<<<dim3(QKVN / 128, SEQ / 128, 1), 256, 0, stream>>>(
      Xb, Wqkvt, bqkv, nullptr, nullptr, Qb, Kb, Vt, SEQ, QKVN, HID, HID, 1);

  attn_kernel<<<1536, 256, 0, stream>>>(Qb, Kb, Vt, AO, Opart, Ml);
  merge_kernel<<<(NH * 1024 * 32) / 256, 256, 0, stream>>>(Opart, Ml, AO);

  // Wo GEMM, split-K=2 (blockIdx.z), partials P0/P1, then reduce
  gemm_bt_kernel<<<dim3(HID / 128, SEQ / 128, 2), 256, 0, stream>>>(
      AO, Wot, nullptr, P0, P1, nullptr, nullptr, nullptr, SEQ, HID, 2048, HID, 0);
  reduce_kernel<<<(SEQ * HID) / 1024, 256, 0, stream>>>(P0, P1, out, SEQ * HID);
}

// Round 7
// 410.238 us; speedup vs baseline: 1.0452x; 1.0277x over previous
//
#include <hip/hip_runtime.h>
#include <hip/hip_bf16.h>

typedef __hip_bfloat16 bf16;
typedef __attribute__((ext_vector_type(8))) __bf16 bf16x8;
typedef __attribute__((ext_vector_type(4))) float f32x4;

#define SEQ 2048
#define HID 4096
#define NH 32
#define NKV 8
#define HD 128
#define KVDIM 1024
#define QKVN 6144

#define MiB (1024 * 1024)

__device__ __forceinline__ void gl_lds16(const void* g, void* lds) {
  __builtin_amdgcn_global_load_lds((const __attribute__((address_space(1))) void*)g,
                                   (__attribute__((address_space(3))) void*)lds,
                                   16, 0, 0);
}

// ---------------- elementwise fp32 -> bf16 ----------------
__global__ void cvt_kernel(const float* __restrict__ in, bf16* __restrict__ out, int n) {
  int i = (blockIdx.x * blockDim.x + threadIdx.x) * 4;
  if (i >= n) return;
  float4 v = *reinterpret_cast<const float4*>(in + i);
  bf16 o[4] = {__float2bfloat16(v.x), __float2bfloat16(v.y),
               __float2bfloat16(v.z), __float2bfloat16(v.w)};
  *reinterpret_cast<short4*>(out + i) = *reinterpret_cast<const short4*>(o);
}

// ---------------- bias concat [4096|1024|1024] ----------------
__global__ void concat_bias_kernel(const float* __restrict__ bq, const float* __restrict__ bk,
                                   const float* __restrict__ bv, float* __restrict__ o) {
  int i = blockIdx.x * blockDim.x + threadIdx.x;
  if (i >= QKVN) return;
  o[i] = (i < HID) ? bq[i] : (i < HID + KVDIM ? bk[i - HID] : bv[i - HID - KVDIM]);
}

// ---------------- merged 4-way weight transpose fp32[HID][C] -> bf16[C][HID] ----------------
// linear tile ranges: [0,16384) Wq, [16384,20480) Wk, [20480,24576) Wv, [24576,40960) Wo
__global__ void transpose_all_kernel(const float* __restrict__ Wq, const float* __restrict__ Wk,
                                     const float* __restrict__ Wv, const float* __restrict__ Wo,
                                     bf16* __restrict__ Wqkvt, bf16* __restrict__ Wot) {
  __shared__ float tile[32][33];
  int t = blockIdx.x;
  const float* in;
  bf16* out;
  int si, xt, yt;
  if (t < 16384)      { in = Wq; out = Wqkvt;                           si = HID;   xt = t & 127; yt = t >> 7; }
  else if (t < 20480) { t -= 16384; in = Wk; out = Wqkvt + (size_t)HID * HID;           si = KVDIM; xt = t & 31; yt = t >> 5; }
  else if (t < 24576) { t -= 20480; in = Wv; out = Wqkvt + (size_t)(HID + KVDIM) * HID; si = KVDIM; xt = t & 31; yt = t >> 5; }
  else                { t -= 24576; in = Wo; out = Wot;                 si = HID;   xt = t & 127; yt = t >> 7; }
  int c0 = xt * 32, r0 = yt * 32;
  int tx = threadIdx.x, ty = threadIdx.y;
#pragma unroll
  for (int i = 0; i < 32; i += 8)
    tile[ty + i][tx] = in[(size_t)(r0 + ty + i) * si + (c0 + tx)];
  __syncthreads();
#pragma unroll
  for (int i = 0; i < 32; i += 8)
    out[(size_t)(c0 + ty + i) * HID + (r0 + tx)] = __float2bfloat16(tile[tx][ty + i]);
}

// ---------------- tiled transpose fp32[R][C](stride si) -> bf16[C][R](stride so) ----------------
__global__ void transpose_cvt_kernel(const float* __restrict__ in, bf16* __restrict__ out,
                                     int si, int so) {
  __shared__ float tile[32][33];
  int c0 = blockIdx.x * 32, r0 = blockIdx.y * 32;
  int tx = threadIdx.x, ty = threadIdx.y;
#pragma unroll
  for (int i = 0; i < 32; i += 8)
    tile[ty + i][tx] = in[(size_t)(r0 + ty + i) * si + (c0 + tx)];
  __syncthreads();
#pragma unroll
  for (int i = 0; i < 32; i += 8)
    out[(size_t)(c0 + ty + i) * so + (r0 + tx)] = __float2bfloat16(tile[tx][ty + i]);
}

// ---------------- RoPE fp32(stride si) -> bf16 (pos = row index) ----------------
__global__ void rope_cvt_kernel(const float* __restrict__ in, bf16* __restrict__ out,
                                int nheads, int hshift, int si) {
  int idx = blockIdx.x * blockDim.x + threadIdx.x;  // over SEQ*nheads*64
  int i = idx & 63;
  int h = (idx >> 6) & (nheads - 1);
  int s = idx >> (6 + hshift);
  if (s >= SEQ) return;
  float inv = __expf(-(float)i * 0.14391156831212787f);  // ln(10000)/64
  float ang = (float)s * inv;
  float sn, cs;
  __sincosf(ang, &sn, &cs);
  size_t bi = (size_t)s * si + (size_t)h * HD + i;
  size_t bo = (size_t)s * ((size_t)nheads * HD) + (size_t)h * HD + i;
  float x1 = in[bi], x2 = in[bi + 64];
  out[bo]      = __float2bfloat16(x1 * cs - x2 * sn);
  out[bo + 64] = __float2bfloat16(x2 * cs + x1 * sn);
}

// ---------------- GEMM: C[M][N] = A[M][K] * Bt[N][K]^T + bias ----------------
// 128x128 tile, BK=64, 4 waves (2x2). Split-K via blockIdx.z: K offset bz*2048,
// output to (bz ? C1 : C0).
__global__ __launch_bounds__(256) void gemm_bt_kernel(
    const bf16* __restrict__ A, const bf16* __restrict__ Bt,
    const float* __restrict__ bias, float* __restrict__ C0, float* __restrict__ C1,
    int N, int Ksub, int lda) {
  __shared__ bf16 As[128 * 64];
  __shared__ bf16 Bs[128 * 64];
  const int tid = threadIdx.x;
  const int lane = tid & 63;
  const int w = tid >> 6;
  const int wm = w >> 1, wn = w & 1;
  const int m0 = blockIdx.y * 128;
  const int n0 = blockIdx.x * 128;
  const int bz = blockIdx.z;
  const bf16* Ab = A + (size_t)bz * 2048;
  const bf16* Btb = Bt + (size_t)bz * 2048;
  float* Cb = bz ? C1 : C0;

  f32x4 acc[4][4];
  const f32x4 z = {0.f, 0.f, 0.f, 0.f};
#pragma unroll
  for (int i = 0; i < 4; i++)
#pragma unroll
    for (int j = 0; j < 4; j++) acc[i][j] = z;

  for (int kk = 0; kk < Ksub; kk += 64) {
#pragma unroll
    for (int it = 0; it < 4; ++it) {
      int c = w * 4 + it;
      int row = c * 8 + (lane >> 3);
      int sb = ((lane & 7) * 16) ^ ((row & 7) << 4);
      gl_lds16(Ab + (size_t)(m0 + row) * lda + kk + (sb >> 1), &As[c * 512]);
      gl_lds16(Btb + (size_t)(n0 + row) * lda + kk + (sb >> 1), &Bs[c * 512]);
    }
    __syncthreads();
#pragma unroll
    for (int ks = 0; ks < 64; ks += 32) {
      bf16x8 a[4], b[4];
#pragma unroll
      for (int mi = 0; mi < 4; ++mi) {
        int r = wm * 64 + mi * 16 + (lane & 15);
        int byt = r * 128 + (((ks + (lane >> 4) * 8) * 2) ^ ((r & 7) << 4));
        a[mi] = *reinterpret_cast<const bf16x8*>(reinterpret_cast<const char*>(As) + byt);
      }
#pragma unroll
      for (int ni = 0; ni < 4; ++ni) {
        int r = wn * 64 + ni * 16 + (lane & 15);
        int byt = r * 128 + (((ks + (lane >> 4) * 8) * 2) ^ ((r & 7) << 4));
        b[ni] = *reinterpret_cast<const bf16x8*>(reinterpret_cast<const char*>(Bs) + byt);
      }
#pragma unroll
      for (int mi = 0; mi < 4; ++mi)
#pragma unroll
        for (int ni = 0; ni < 4; ++ni)
          acc[mi][ni] = __builtin_amdgcn_mfma_f32_16x16x32_bf16(a[mi], b[ni], acc[mi][ni], 0, 0, 0);
    }
    __syncthreads();
  }
#pragma unroll
  for (int ni = 0; ni < 4; ++ni) {
    int col = n0 + wn * 64 + ni * 16 + (lane & 15);
    float bv = bias ? bias[col] : 0.0f;
#pragma unroll
    for (int mi = 0; mi < 4; ++mi) {
      int rbase = m0 + wm * 64 + mi * 16 + (lane >> 4) * 4;
#pragma unroll
      for (int r = 0; r < 4; ++r)
        Cb[(size_t)(rbase + r) * N + col] = acc[mi][ni][r] + bv;
    }
  }
}

// ---------------- reduce: out = P0 + P1 ----------------
__global__ void reduce_kernel(const float* __restrict__ P0, const float* __restrict__ P1,
                              float* __restrict__ out, int n) {
  int i = (blockIdx.x * blockDim.x + threadIdx.x) * 4;
  if (i >= n) return;
  float4 a = *reinterpret_cast<const float4*>(P0 + i);
  float4 b = *reinterpret_cast<const float4*>(P1 + i);
  float4 o = {a.x + b.x, a.y + b.y, a.z + b.z, a.w + b.w};
  *reinterpret_cast<float4*>(out + i) = o;
}

// ---------------- flash attention with KV-split load balancing ----------------
__global__ __launch_bounds__(256) void attn_kernel(
    const bf16* __restrict__ Q,   // [SEQ][HID]
    const bf16* __restrict__ Kb,  // [SEQ][KVDIM]
    const bf16* __restrict__ Vt,  // [KVDIM][SEQ]
    bf16* __restrict__ AO,        // [SEQ][HID]
    float* __restrict__ Opart,    // [2][NH][1024][HD]
    float* __restrict__ Ml) {     // [2][NH][1024][2]
  __shared__ bf16 Ks[64 * 128];
  __shared__ bf16 Vs[128 * 64];
  __shared__ bf16 Ps[4][16 * 64];
  const int tid = threadIdx.x, lane = tid & 63, w = tid >> 6;
  const int b = blockIdx.x;
  const int H = b & 31;
  const int tt = b >> 5;
  int qb, lo, hi, half;
  bool split;
  if (tt < 32) {
    qb = 16 + ((31 - tt) >> 1);
    half = tt & 1;
    int n = qb + 1, mid = n >> 1;
    lo = half ? mid : 0;
    hi = half ? n : mid;
    split = true;
  } else {
    qb = 47 - tt;
    half = 0;
    lo = 0;
    hi = qb + 1;
    split = false;
  }
  const int kvh = H >> 2;
  const int qw = qb * 64 + w * 16;

  bf16x8 aq[4];
#pragma unroll
  for (int kd = 0; kd < 4; ++kd) {
    int row = qw + (lane & 15);
    int d = kd * 32 + (lane >> 4) * 8;
    aq[kd] = *reinterpret_cast<const bf16x8*>(Q + (size_t)row * HID + H * HD + d);
  }

  float m_run[4], l_run[4];
  f32x4 o[8];
  const f32x4 z = {0.f, 0.f, 0.f, 0.f};
#pragma unroll
  for (int r = 0; r < 4; ++r) { m_run[r] = -1e30f; l_run[r] = 0.0f; }
#pragma unroll
  for (int dt = 0; dt < 8; ++dt) o[dt] = z;

  const float scale = 0.08838834764831845f;

  for (int t = lo; t < hi; ++t) {
    int kvbase = t * 64;
#pragma unroll
    for (int it = 0; it < 4; ++it) {
      int c = w * 4 + it;
      int row = c * 4 + (lane >> 4);
      int sb = ((lane & 15) * 16) ^ ((row & 7) << 4);
      gl_lds16(Kb + (size_t)(kvbase + row) * KVDIM + kvh * HD + (sb >> 1), &Ks[c * 512]);
    }
#pragma unroll
    for (int it = 0; it < 4; ++it) {
      int c = w * 4 + it;
      int row = c * 8 + (lane >> 3);
      int sb = ((lane & 7) * 16) ^ ((row & 7) << 4);
      gl_lds16(Vt + (size_t)(kvh * HD + row) * SEQ + kvbase + (sb >> 1), &Vs[c * 512]);
    }
    __syncthreads();

    f32x4 sf[4];
#pragma unroll
    for (int j = 0; j < 4; ++j) sf[j] = z;
#pragma unroll
    for (int j = 0; j < 4; ++j) {
#pragma unroll
      for (int kd = 0; kd < 4; ++kd) {
        int r = j * 16 + (lane & 15);
        int byt = r * 256 + (((kd * 32 + (lane >> 4) * 8) * 2) ^ ((r & 7) << 4));
        bf16x8 bfr = *reinterpret_cast<const bf16x8*>(reinterpret_cast<const char*>(Ks) + byt);
        sf[j] = __builtin_amdgcn_mfma_f32_16x16x32_bf16(aq[kd], bfr, sf[j], 0, 0, 0);
      }
    }

    float vals[4][4];
    bool diag = (t == qb);
#pragma unroll
    for (int j = 0; j < 4; ++j)
#pragma unroll
      for (int r = 0; r < 4; ++r) {
        float v = sf[j][r] * scale;
        if (diag) {
          int qa = qw + (lane >> 4) * 4 + r;
          int ka = kvbase + j * 16 + (lane & 15);
          if (ka > qa) v = -1e30f;
        }
        vals[j][r] = v;
      }

    float mt[4], alpha[4];
#pragma unroll
    for (int r = 0; r < 4; ++r) {
      float m = fmaxf(fmaxf(vals[0][r], vals[1][r]), fmaxf(vals[2][r], vals[3][r]));
#pragma unroll
      for (int sh = 8; sh >= 1; sh >>= 1) m = fmaxf(m, __shfl_xor(m, sh, 16));
      float mn = fmaxf(m_run[r], m);
      alpha[r] = __expf(m_run[r] - mn);
      m_run[r] = mn;
      mt[r] = mn;
    }

    float rs[4] = {0.f, 0.f, 0.f, 0.f};
#pragma unroll
    for (int j = 0; j < 4; ++j)
#pragma unroll
      for (int r = 0; r < 4; ++r) {
        float p = __expf(vals[j][r] - mt[r]);
        rs[r] += p;
        int prow = (lane >> 4) * 4 + r;
        int pcol = j * 16 + (lane & 15);
        int byt = prow * 128 + ((pcol * 2) ^ ((prow & 7) << 4));
        *reinterpret_cast<bf16*>(reinterpret_cast<char*>(&Ps[w][0]) + byt) = __float2bfloat16(p);
      }
#pragma unroll
    for (int r = 0; r < 4; ++r) {
#pragma unroll
      for (int sh = 8; sh >= 1; sh >>= 1) rs[r] += __shfl_xor(rs[r], sh, 16);
      l_run[r] = l_run[r] * alpha[r] + rs[r];
    }
#pragma unroll
    for (int dt = 0; dt < 8; ++dt)
#pragma unroll
      for (int r = 0; r < 4; ++r) o[dt][r] *= alpha[r];

    bf16x8 pa[2];
#pragma unroll
    for (int ks = 0; ks < 2; ++ks) {
      int prow = lane & 15;
      int byt = prow * 128 + (((ks * 32 + (lane >> 4) * 8) * 2) ^ ((prow & 7) << 4));
      pa[ks] = *reinterpret_cast<const bf16x8*>(reinterpret_cast<const char*>(&Ps[w][0]) + byt);
    }
#pragma unroll
    for (int dt = 0; dt < 8; ++dt)
#pragma unroll
      for (int ks = 0; ks < 2; ++ks) {
        int vrow = dt * 16 + (lane & 15);
        int byt = vrow * 128 + (((ks * 32 + (lane >> 4) * 8) * 2) ^ ((vrow & 7) << 4));
        bf16x8 vb = *reinterpret_cast<const bf16x8*>(reinterpret_cast<const char*>(Vs) + byt);
        o[dt] = __builtin_amdgcn_mfma_f32_16x16x32_bf16(pa[ks], vb, o[dt], 0, 0, 0);
      }
    __syncthreads();
  }

  if (!split) {
#pragma unroll
    for (int dt = 0; dt < 8; ++dt)
#pragma unroll
      for (int r = 0; r < 4; ++r) {
        int qa = qw + (lane >> 4) * 4 + r;
        int d = dt * 16 + (lane & 15);
        AO[(size_t)qa * HID + H * HD + d] = __float2bfloat16(o[dt][r] / l_run[r]);
      }
  } else {
    size_t pbase = ((size_t)(half * NH + H) * 1024);
#pragma unroll
    for (int dt = 0; dt < 8; ++dt)
#pragma unroll
      for (int r = 0; r < 4; ++r) {
        int qa = qw + (lane >> 4) * 4 + r;
        int d = dt * 16 + (lane & 15);
        Opart[(pbase + (qa - 1024)) * HD + d] = o[dt][r];
      }
    if ((lane & 15) == 0) {
#pragma unroll
      for (int r = 0; r < 4; ++r) {
        int qa = qw + (lane >> 4) * 4 + r;
        Ml[(pbase + (qa - 1024)) * 2 + 0] = m_run[r];
        Ml[(pbase + (qa - 1024)) * 2 + 1] = l_run[r];
      }
    }
  }
}

// ---------------- merge split-attention partials ----------------
__global__ __launch_bounds__(256) void merge_kernel(
    const float* __restrict__ Opart, const float* __restrict__ Ml,
    bf16* __restrict__ AO) {
  int i = blockIdx.x * 256 + threadIdx.x;
  int dq = (i & 31) << 2;
  int row = (i >> 5) & 1023;
  int H = i >> 15;
  size_t b1 = (size_t)H * 1024 + row;
  size_t b2 = (size_t)(NH + H) * 1024 + row;
  float m1 = Ml[b1 * 2], l1 = Ml[b1 * 2 + 1];
  float m2 = Ml[b2 * 2], l2 = Ml[b2 * 2 + 1];
  float M = fmaxf(m1, m2);
  float w1 = __expf(m1 - M), w2 = __expf(m2 - M);
  float inv = 1.0f / (l1 * w1 + l2 * w2);
  float4 o1 = *reinterpret_cast<const float4*>(Opart + b1 * HD + dq);
  float4 o2 = *reinterpret_cast<const float4*>(Opart + b2 * HD + dq);
  bf16 o[4] = {__float2bfloat16((o1.x * w1 + o2.x * w2) * inv),
               __float2bfloat16((o1.y * w1 + o2.y * w2) * inv),
               __float2bfloat16((o1.z * w1 + o2.z * w2) * inv),
               __float2bfloat16((o1.w * w1 + o2.w * w2) * inv)};
  *reinterpret_cast<short4*>(AO + (size_t)(1024 + row) * HID + H * HD + dq) =
      *reinterpret_cast<const short4*>(o);
}

extern "C" void kernel_launch(void* const* d_in, const int* in_sizes, int n_in,
                              void* d_out, int out_size, void* d_ws, size_t ws_size,
                              hipStream_t stream) {
  const float* hidden = (const float*)d_in[0];
  const float* Wq = (const float*)d_in[2];
  const float* bq = (const float*)d_in[3];
  const float* Wk = (const float*)d_in[4];
  const float* bk = (const float*)d_in[5];
  const float* Wv = (const float*)d_in[6];
  const float* bv = (const float*)d_in[7];
  const float* Wo = (const float*)d_in[8];
  float* out = (float*)d_out;

  // workspace map (168 MiB total, R1-proven size):
  char* ws = (char*)d_ws;
  bf16*  Wqkvt = (bf16*)(ws + (size_t)0 * MiB);    // 48 MiB  [Q|K|V]^T bf16
  bf16*  Xb    = (bf16*)(ws + (size_t)48 * MiB);   // 16 MiB
  float* Cqkv  = (float*)(ws + (size_t)64 * MiB);  // 48 MiB  fp32 QKV out
  bf16*  Wot   = (bf16*)(ws + (size_t)112 * MiB);  // 32 MiB
  bf16*  Qb    = (bf16*)(ws + (size_t)144 * MiB);  // 16 MiB
  bf16*  Kb    = (bf16*)(ws + (size_t)160 * MiB);  // 4 MiB
  bf16*  Vt    = (bf16*)(ws + (size_t)164 * MiB);  // 4 MiB  (ends at 168 MiB)
  // stream-ordered aliases:
  float* bqkv  = (float*)Qb;                        // written pre-GEMM, consumed by GEMM,
                                                    // overwritten by rope_q afterwards
  bf16*  AO    = (bf16*)Cqkv;                       // Cqkv dead after rope/V-transpose
  float* Opart = (float*)Wqkvt;                     // Wqkvt dead after QKV GEMM (32 MiB)
  float* Ml    = (float*)(ws + (size_t)32 * MiB);   // 0.5 MiB, still inside dead Wqkvt
  float* P0    = (float*)Wqkvt;                     // Opart dead after merge
  float* P1    = (float*)(ws + (size_t)80 * MiB);   // dead Cqkv beyond AO (32 MiB)

  cvt_kernel<<<(SEQ * HID) / 1024, 256, 0, stream>>>(hidden, Xb, SEQ * HID);
  concat_bias_kernel<<<QKVN / 256, 256, 0, stream>>>(bq, bk, bv, bqkv);
  transpose_all_kernel<<<40960, dim3(32, 8), 0, stream>>>(Wq, Wk, Wv, Wo, Wqkvt, Wot);

  // QKV GEMM (pure): Cqkv = Xb * Wqkvt^T + bqkv
  gemm_bt_kernel<<<dim3(QKVN / 128, SEQ / 128, 1), 256, 0, stream>>>(
      Xb, Wqkvt, bqkv, Cqkv, nullptr, QKVN, HID, HID);

  rope_cvt_kernel<<<(SEQ * NH * 64) / 256, 256, 0, stream>>>(Cqkv, Qb, NH, 5, QKVN);
  rope_cvt_kernel<<<(SEQ * NKV * 64) / 256, 256, 0, stream>>>(Cqkv + HID, Kb, NKV, 3, QKVN);
  transpose_cvt_kernel<<<dim3(KVDIM / 32, SEQ / 32), dim3(32, 8), 0, stream>>>(
      Cqkv + HID + KVDIM, Vt, QKVN, SEQ);

  attn_kernel<<<1536, 256, 0, stream>>>(Qb, Kb, Vt, AO, Opart, Ml);
  merge_kernel<<<(NH * 1024 * 32) / 256, 256, 0, stream>>>(Opart, Ml, AO);

  // Wo GEMM, split-K=2 (blockIdx.z), partials P0/P1, then reduce
  gemm_bt_kernel<<<dim3(HID / 128, SEQ / 128, 2), 256, 0, stream>>>(
      AO, Wot, nullptr, P0, P1, HID, 2048, HID);
  reduce_kernel<<<(SEQ * HID) / 1024, 256, 0, stream>>>(P0, P1, out, SEQ * HID);
}

// Round 8
// 379.768 us; speedup vs baseline: 1.1290x; 1.0802x over previous
//
#include <hip/hip_runtime.h>
#include <hip/hip_bf16.h>

typedef __hip_bfloat16 bf16;
typedef __attribute__((ext_vector_type(8))) __bf16 bf16x8;
typedef __attribute__((ext_vector_type(4))) float f32x4;

#define SEQ 2048
#define HID 4096
#define NH 32
#define NKV 8
#define HD 128
#define KVDIM 1024
#define QKVN 6144

#define MiB (1024 * 1024)

__device__ __forceinline__ void gl_lds16(const void* g, void* lds) {
  __builtin_amdgcn_global_load_lds((const __attribute__((address_space(1))) void*)g,
                                   (__attribute__((address_space(3))) void*)lds,
                                   16, 0, 0);
}

// ---------------- elementwise fp32 -> bf16 ----------------
__global__ void cvt_kernel(const float* __restrict__ in, bf16* __restrict__ out, int n) {
  int i = (blockIdx.x * blockDim.x + threadIdx.x) * 4;
  if (i >= n) return;
  float4 v = *reinterpret_cast<const float4*>(in + i);
  bf16 o[4] = {__float2bfloat16(v.x), __float2bfloat16(v.y),
               __float2bfloat16(v.z), __float2bfloat16(v.w)};
  *reinterpret_cast<short4*>(out + i) = *reinterpret_cast<const short4*>(o);
}

// ---------------- bias concat [4096|1024|1024] ----------------
__global__ void concat_bias_kernel(const float* __restrict__ bq, const float* __restrict__ bk,
                                   const float* __restrict__ bv, float* __restrict__ o) {
  int i = blockIdx.x * blockDim.x + threadIdx.x;
  if (i >= QKVN) return;
  o[i] = (i < HID) ? bq[i] : (i < HID + KVDIM ? bk[i - HID] : bv[i - HID - KVDIM]);
}

// ---------------- merged 4-way weight transpose fp32[HID][C] -> bf16[C][HID] ----------------
__global__ void transpose_all_kernel(const float* __restrict__ Wq, const float* __restrict__ Wk,
                                     const float* __restrict__ Wv, const float* __restrict__ Wo,
                                     bf16* __restrict__ Wqkvt, bf16* __restrict__ Wot) {
  __shared__ float tile[32][33];
  int t = blockIdx.x;
  const float* in;
  bf16* out;
  int si, xt, yt;
  if (t < 16384)      { in = Wq; out = Wqkvt;                           si = HID;   xt = t & 127; yt = t >> 7; }
  else if (t < 20480) { t -= 16384; in = Wk; out = Wqkvt + (size_t)HID * HID;           si = KVDIM; xt = t & 31; yt = t >> 5; }
  else if (t < 24576) { t -= 20480; in = Wv; out = Wqkvt + (size_t)(HID + KVDIM) * HID; si = KVDIM; xt = t & 31; yt = t >> 5; }
  else                { t -= 24576; in = Wo; out = Wot;                 si = HID;   xt = t & 127; yt = t >> 7; }
  int c0 = xt * 32, r0 = yt * 32;
  int tx = threadIdx.x, ty = threadIdx.y;
#pragma unroll
  for (int i = 0; i < 32; i += 8)
    tile[ty + i][tx] = in[(size_t)(r0 + ty + i) * si + (c0 + tx)];
  __syncthreads();
#pragma unroll
  for (int i = 0; i < 32; i += 8)
    out[(size_t)(c0 + ty + i) * HID + (r0 + tx)] = __float2bfloat16(tile[tx][ty + i]);
}

// ---------------- tiled transpose fp32[R][C](stride si) -> bf16[C][R](stride so) ----------------
__global__ void transpose_cvt_kernel(const float* __restrict__ in, bf16* __restrict__ out,
                                     int si, int so) {
  __shared__ float tile[32][33];
  int c0 = blockIdx.x * 32, r0 = blockIdx.y * 32;
  int tx = threadIdx.x, ty = threadIdx.y;
#pragma unroll
  for (int i = 0; i < 32; i += 8)
    tile[ty + i][tx] = in[(size_t)(r0 + ty + i) * si + (c0 + tx)];
  __syncthreads();
#pragma unroll
  for (int i = 0; i < 32; i += 8)
    out[(size_t)(c0 + ty + i) * so + (r0 + tx)] = __float2bfloat16(tile[tx][ty + i]);
}

// ---------------- RoPE fp32(stride si) -> bf16 (pos = row index) ----------------
__global__ void rope_cvt_kernel(const float* __restrict__ in, bf16* __restrict__ out,
                                int nheads, int hshift, int si) {
  int idx = blockIdx.x * blockDim.x + threadIdx.x;
  int i = idx & 63;
  int h = (idx >> 6) & (nheads - 1);
  int s = idx >> (6 + hshift);
  if (s >= SEQ) return;
  float inv = __expf(-(float)i * 0.14391156831212787f);  // ln(10000)/64
  float ang = (float)s * inv;
  float sn, cs;
  __sincosf(ang, &sn, &cs);
  size_t bi = (size_t)s * si + (size_t)h * HD + i;
  size_t bo = (size_t)s * ((size_t)nheads * HD) + (size_t)h * HD + i;
  float x1 = in[bi], x2 = in[bi + 64];
  out[bo]      = __float2bfloat16(x1 * cs - x2 * sn);
  out[bo + 64] = __float2bfloat16(x2 * cs + x1 * sn);
}

// ---------------- 256x256 8-phase GEMM: C[M][N] = A[M][K]*Bt[N][K]^T (+bias) ----------------
// 512 threads = 8 waves (2 M x 4 N); per-wave 128x64 output (acc[8][4] f32x4).
// BK=64; LDS = 2 buf x {A 256x64 | B 256x64} bf16 = 128 KiB, halves of 128 rows.
// Per K-tile 4 phases (C-quadrants): P1 rd a0-3,b0-1 ->Q00; P2 rd b2-3 ->Q01;
// P3 rd a4-7 ->Q11; P4 (resident) ->Q10. Stages: P1: A1(t+1); P3: B0,B1(t+2);
// P4: A0(t+2) + vmcnt(6). Dead-slot-safe: A-halves consumed after P3, B after P2.
// Split-K via blockIdx.z (offset bz*Ksub, out to C1 when bz==1).
#define BARRIER() __builtin_amdgcn_s_barrier()
#define LGKM0()                                          \
  {                                                      \
    asm volatile("s_waitcnt lgkmcnt(0)" ::: "memory");   \
    __builtin_amdgcn_sched_barrier(0);                   \
  }
#define MFMA_ACC(d, x, y) d = __builtin_amdgcn_mfma_f32_16x16x32_bf16(x, y, d, 0, 0, 0)

__global__ __launch_bounds__(512, 2) void gemm256_kernel(
    const bf16* __restrict__ A, const bf16* __restrict__ Bt,
    const float* __restrict__ bias, float* __restrict__ C0, float* __restrict__ C1,
    int N, int Ksub, int lda) {
  __shared__ bf16 lds[2][4][128 * 64];  // [buf][A0,A1,B0,B1]
  const int tid = threadIdx.x;
  const int lane = tid & 63;
  const int w = tid >> 6;
  const int wr = w >> 2, wc = w & 3;
  const int m0 = blockIdx.y * 256;
  const int n0 = blockIdx.x * 256;
  const int bz = blockIdx.z;
  const bf16* Ab = A + (size_t)bz * Ksub;
  const bf16* Btb = Bt + (size_t)bz * Ksub;
  float* Cb = bz ? C1 : C0;
  const int nt = Ksub >> 6;

  // stage one 128x64 half-tile slice (2 gl_lds per wave), pre-swizzled source
#define STAGE(buf, half, t)                                                     \
  {                                                                             \
    const bf16* _s = ((half) < 2) ? Ab : Btb;                                   \
    int _g0 = (((half) < 2) ? m0 : n0) + ((half) & 1) * 128;                    \
    _Pragma("unroll")                                                           \
    for (int _it = 0; _it < 2; ++_it) {                                         \
      int _row = w * 16 + _it * 8 + (lane >> 3);                                \
      int _ch = (lane & 7) ^ (_row & 7);                                        \
      gl_lds16(_s + (size_t)(_g0 + _row) * lda + (size_t)(t) * 64 + _ch * 8,    \
               &lds[buf][half][(w * 16 + _it * 8) * 64]);                       \
    }                                                                           \
  }

  auto rdA = [&](int cur, int mi, int ks) {
    int rr = mi * 16 + (lane & 15);
    int byt = rr * 128 + (((ks * 32 + (lane >> 4) * 8) * 2) ^ ((rr & 7) << 4));
    return *reinterpret_cast<const bf16x8*>(
        reinterpret_cast<const char*>(&lds[cur][wr][0]) + byt);
  };
  auto rdB = [&](int cur, int ni, int ks) {
    int rr = (wc & 1) * 64 + ni * 16 + (lane & 15);
    int byt = rr * 128 + (((ks * 32 + (lane >> 4) * 8) * 2) ^ ((rr & 7) << 4));
    return *reinterpret_cast<const bf16x8*>(
        reinterpret_cast<const char*>(&lds[cur][2 + (wc >> 1)][0]) + byt);
  };

  f32x4 acc[8][4];
  const f32x4 z = {0.f, 0.f, 0.f, 0.f};
#pragma unroll
  for (int i = 0; i < 8; ++i)
#pragma unroll
    for (int j = 0; j < 4; ++j) acc[i][j] = z;

  // prologue: tile0 fully; tile1 B0,B1,A0 (A1 comes at P1 of t=0)
  STAGE(0, 0, 0); STAGE(0, 1, 0); STAGE(0, 2, 0); STAGE(0, 3, 0);
  STAGE(1, 2, 1); STAGE(1, 3, 1); STAGE(1, 0, 1);
  asm volatile("s_waitcnt vmcnt(6)" ::: "memory");  // tile0 landed; 3 halves in flight
  BARRIER();

  bf16x8 a[4][2], b[4][2];
  int cur = 0;
  for (int t = 0; t < nt; ++t, cur ^= 1) {
    // ---- P1: rd a0-3 + b0-1; stage A1(t+1); MFMA Q00
#pragma unroll
    for (int mi = 0; mi < 4; ++mi) { a[mi][0] = rdA(cur, mi, 0); a[mi][1] = rdA(cur, mi, 1); }
#pragma unroll
    for (int ni = 0; ni < 2; ++ni) { b[ni][0] = rdB(cur, ni, 0); b[ni][1] = rdB(cur, ni, 1); }
    if (t + 1 < nt) STAGE(cur ^ 1, 1, t + 1);
    BARRIER();
    LGKM0();
    __builtin_amdgcn_s_setprio(1);
#pragma unroll
    for (int mi = 0; mi < 4; ++mi)
#pragma unroll
      for (int ni = 0; ni < 2; ++ni) {
        MFMA_ACC(acc[mi][ni], a[mi][0], b[ni][0]);
        MFMA_ACC(acc[mi][ni], a[mi][1], b[ni][1]);
      }
    __builtin_amdgcn_s_setprio(0);
    BARRIER();
    // ---- P2: rd b2-3; MFMA Q01
#pragma unroll
    for (int ni = 2; ni < 4; ++ni) { b[ni][0] = rdB(cur, ni, 0); b[ni][1] = rdB(cur, ni, 1); }
    BARRIER();
    LGKM0();
    __builtin_amdgcn_s_setprio(1);
#pragma unroll
    for (int mi = 0; mi < 4; ++mi)
#pragma unroll
      for (int ni = 2; ni < 4; ++ni) {
        MFMA_ACC(acc[mi][ni], a[mi][0], b[ni][0]);
        MFMA_ACC(acc[mi][ni], a[mi][1], b[ni][1]);
      }
    __builtin_amdgcn_s_setprio(0);
    BARRIER();
    // ---- P3: rd a4-7; stage B0,B1(t+2); MFMA Q11
#pragma unroll
    for (int mi = 0; mi < 4; ++mi) { a[mi][0] = rdA(cur, mi + 4, 0); a[mi][1] = rdA(cur, mi + 4, 1); }
    if (t + 2 < nt) { STAGE(cur, 2, t + 2); STAGE(cur, 3, t + 2); }
    BARRIER();
    LGKM0();
    __builtin_amdgcn_s_setprio(1);
#pragma unroll
    for (int mi = 0; mi < 4; ++mi)
#pragma unroll
      for (int ni = 2; ni < 4; ++ni) {
        MFMA_ACC(acc[mi + 4][ni], a[mi][0], b[ni][0]);
        MFMA_ACC(acc[mi + 4][ni], a[mi][1], b[ni][1]);
      }
    __builtin_amdgcn_s_setprio(0);
    BARRIER();
    // ---- P4: stage A0(t+2); counted vmcnt; MFMA Q10
    if (t + 2 < nt) STAGE(cur, 0, t + 2);
    if (t + 2 < nt) {
      asm volatile("s_waitcnt vmcnt(6)" ::: "memory");  // t+1 fully landed
    } else if (t + 1 < nt) {
      asm volatile("s_waitcnt vmcnt(0)" ::: "memory");
    }
    BARRIER();
    __builtin_amdgcn_s_setprio(1);
#pragma unroll
    for (int mi = 0; mi < 4; ++mi)
#pragma unroll
      for (int ni = 0; ni < 2; ++ni) {
        MFMA_ACC(acc[mi + 4][ni], a[mi][0], b[ni][0]);
        MFMA_ACC(acc[mi + 4][ni], a[mi][1], b[ni][1]);
      }
    __builtin_amdgcn_s_setprio(0);
    BARRIER();
  }

  // epilogue: C write (+bias)
#pragma unroll
  for (int ni = 0; ni < 4; ++ni) {
    int col = n0 + wc * 64 + ni * 16 + (lane & 15);
    float bv = bias ? bias[col] : 0.0f;
#pragma unroll
    for (int mi = 0; mi < 8; ++mi) {
      int rbase = m0 + wr * 128 + mi * 16 + (lane >> 4) * 4;
#pragma unroll
      for (int r = 0; r < 4; ++r)
        Cb[(size_t)(rbase + r) * N + col] = acc[mi][ni][r] + bv;
    }
  }
#undef STAGE
}

// ---------------- reduce: out = P0 + P1 ----------------
__global__ void reduce_kernel(const float* __restrict__ P0, const float* __restrict__ P1,
                              float* __restrict__ out, int n) {
  int i = (blockIdx.x * blockDim.x + threadIdx.x) * 4;
  if (i >= n) return;
  float4 a = *reinterpret_cast<const float4*>(P0 + i);
  float4 b = *reinterpret_cast<const float4*>(P1 + i);
  float4 o = {a.x + b.x, a.y + b.y, a.z + b.z, a.w + b.w};
  *reinterpret_cast<float4*>(out + i) = o;
}

// ---------------- flash attention with KV-split load balancing ----------------
__global__ __launch_bounds__(256) void attn_kernel(
    const bf16* __restrict__ Q,   // [SEQ][HID]
    const bf16* __restrict__ Kb,  // [SEQ][KVDIM]
    const bf16* __restrict__ Vt,  // [KVDIM][SEQ]
    bf16* __restrict__ AO,        // [SEQ][HID]
    float* __restrict__ Opart,    // [2][NH][1024][HD]
    float* __restrict__ Ml) {     // [2][NH][1024][2]
  __shared__ bf16 Ks[64 * 128];
  __shared__ bf16 Vs[128 * 64];
  __shared__ bf16 Ps[4][16 * 64];
  const int tid = threadIdx.x, lane = tid & 63, w = tid >> 6;
  const int b = blockIdx.x;
  const int H = b & 31;
  const int tt = b >> 5;
  int qb, lo, hi, half;
  bool split;
  if (tt < 32) {
    qb = 16 + ((31 - tt) >> 1);
    half = tt & 1;
    int n = qb + 1, mid = n >> 1;
    lo = half ? mid : 0;
    hi = half ? n : mid;
    split = true;
  } else {
    qb = 47 - tt;
    half = 0;
    lo = 0;
    hi = qb + 1;
    split = false;
  }
  const int kvh = H >> 2;
  const int qw = qb * 64 + w * 16;

  bf16x8 aq[4];
#pragma unroll
  for (int kd = 0; kd < 4; ++kd) {
    int row = qw + (lane & 15);
    int d = kd * 32 + (lane >> 4) * 8;
    aq[kd] = *reinterpret_cast<const bf16x8*>(Q + (size_t)row * HID + H * HD + d);
  }

  float m_run[4], l_run[4];
  f32x4 o[8];
  const f32x4 z = {0.f, 0.f, 0.f, 0.f};
#pragma unroll
  for (int r = 0; r < 4; ++r) { m_run[r] = -1e30f; l_run[r] = 0.0f; }
#pragma unroll
  for (int dt = 0; dt < 8; ++dt) o[dt] = z;

  const float scale = 0.08838834764831845f;

  for (int t = lo; t < hi; ++t) {
    int kvbase = t * 64;
#pragma unroll
    for (int it = 0; it < 4; ++it) {
      int c = w * 4 + it;
      int row = c * 4 + (lane >> 4);
      int sb = ((lane & 15) * 16) ^ ((row & 7) << 4);
      gl_lds16(Kb + (size_t)(kvbase + row) * KVDIM + kvh * HD + (sb >> 1), &Ks[c * 512]);
    }
#pragma unroll
    for (int it = 0; it < 4; ++it) {
      int c = w * 4 + it;
      int row = c * 8 + (lane >> 3);
      int sb = ((lane & 7) * 16) ^ ((row & 7) << 4);
      gl_lds16(Vt + (size_t)(kvh * HD + row) * SEQ + kvbase + (sb >> 1), &Vs[c * 512]);
    }
    __syncthreads();

    f32x4 sf[4];
#pragma unroll
    for (int j = 0; j < 4; ++j) sf[j] = z;
#pragma unroll
    for (int j = 0; j < 4; ++j) {
#pragma unroll
      for (int kd = 0; kd < 4; ++kd) {
        int r = j * 16 + (lane & 15);
        int byt = r * 256 + (((kd * 32 + (lane >> 4) * 8) * 2) ^ ((r & 7) << 4));
        bf16x8 bfr = *reinterpret_cast<const bf16x8*>(reinterpret_cast<const char*>(Ks) + byt);
        sf[j] = __builtin_amdgcn_mfma_f32_16x16x32_bf16(aq[kd], bfr, sf[j], 0, 0, 0);
      }
    }

    float vals[4][4];
    bool diag = (t == qb);
#pragma unroll
    for (int j = 0; j < 4; ++j)
#pragma unroll
      for (int r = 0; r < 4; ++r) {
        float v = sf[j][r] * scale;
        if (diag) {
          int qa = qw + (lane >> 4) * 4 + r;
          int ka = kvbase + j * 16 + (lane & 15);
          if (ka > qa) v = -1e30f;
        }
        vals[j][r] = v;
      }

    float mt[4], alpha[4];
#pragma unroll
    for (int r = 0; r < 4; ++r) {
      float m = fmaxf(fmaxf(vals[0][r], vals[1][r]), fmaxf(vals[2][r], vals[3][r]));
#pragma unroll
      for (int sh = 8; sh >= 1; sh >>= 1) m = fmaxf(m, __shfl_xor(m, sh, 16));
      float mn = fmaxf(m_run[r], m);
      alpha[r] = __expf(m_run[r] - mn);
      m_run[r] = mn;
      mt[r] = mn;
    }

    float rs[4] = {0.f, 0.f, 0.f, 0.f};
#pragma unroll
    for (int j = 0; j < 4; ++j)
#pragma unroll
      for (int r = 0; r < 4; ++r) {
        float p = __expf(vals[j][r] - mt[r]);
        rs[r] += p;
        int prow = (lane >> 4) * 4 + r;
        int pcol = j * 16 + (lane & 15);
        int byt = prow * 128 + ((pcol * 2) ^ ((prow & 7) << 4));
        *reinterpret_cast<bf16*>(reinterpret_cast<char*>(&Ps[w][0]) + byt) = __float2bfloat16(p);
      }
#pragma unroll
    for (int r = 0; r < 4; ++r) {
#pragma unroll
      for (int sh = 8; sh >= 1; sh >>= 1) rs[r] += __shfl_xor(rs[r], sh, 16);
      l_run[r] = l_run[r] * alpha[r] + rs[r];
    }
#pragma unroll
    for (int dt = 0; dt < 8; ++dt)
#pragma unroll
      for (int r = 0; r < 4; ++r) o[dt][r] *= alpha[r];

    bf16x8 pa[2];
#pragma unroll
    for (int ks = 0; ks < 2; ++ks) {
      int prow = lane & 15;
      int byt = prow * 128 + (((ks * 32 + (lane >> 4) * 8) * 2) ^ ((prow & 7) << 4));
      pa[ks] = *reinterpret_cast<const bf16x8*>(reinterpret_cast<const char*>(&Ps[w][0]) + byt);
    }
#pragma unroll
    for (int dt = 0; dt < 8; ++dt)
#pragma unroll
      for (int ks = 0; ks < 2; ++ks) {
        int vrow = dt * 16 + (lane & 15);
        int byt = vrow * 128 + (((ks * 32 + (lane >> 4) * 8) * 2) ^ ((vrow & 7) << 4));
        bf16x8 vb = *reinterpret_cast<const bf16x8*>(reinterpret_cast<const char*>(Vs) + byt);
        o[dt] = __builtin_amdgcn_mfma_f32_16x16x32_bf16(pa[ks], vb, o[dt], 0, 0, 0);
      }
    __syncthreads();
  }

  if (!split) {
#pragma unroll
    for (int dt = 0; dt < 8; ++dt)
#pragma unroll
      for (int r = 0; r < 4; ++r) {
        int qa = qw + (lane >> 4) * 4 + r;
        int d = dt * 16 + (lane & 15);
        AO[(size_t)qa * HID + H * HD + d] = __float2bfloat16(o[dt][r] / l_run[r]);
      }
  } else {
    size_t pbase = ((size_t)(half * NH + H) * 1024);
#pragma unroll
    for (int dt = 0; dt < 8; ++dt)
#pragma unroll
      for (int r = 0; r < 4; ++r) {
        int qa = qw + (lane >> 4) * 4 + r;
        int d = dt * 16 + (lane & 15);
        Opart[(pbase + (qa - 1024)) * HD + d] = o[dt][r];
      }
    if ((lane & 15) == 0) {
#pragma unroll
      for (int r = 0; r < 4; ++r) {
        int qa = qw + (lane >> 4) * 4 + r;
        Ml[(pbase + (qa - 1024)) * 2 + 0] = m_run[r];
        Ml[(pbase + (qa - 1024)) * 2 + 1] = l_run[r];
      }
    }
  }
}

// ---------------- merge split-attention partials ----------------
__global__ __launch_bounds__(256) void merge_kernel(
    const float* __restrict__ Opart, const float* __restrict__ Ml,
    bf16* __restrict__ AO) {
  int i = blockIdx.x * 256 + threadIdx.x;
  int dq = (i & 31) << 2;
  int row = (i >> 5) & 1023;
  int H = i >> 15;
  size_t b1 = (size_t)H * 1024 + row;
  size_t b2 = (size_t)(NH + H) * 1024 + row;
  float m1 = Ml[b1 * 2], l1 = Ml[b1 * 2 + 1];
  float m2 = Ml[b2 * 2], l2 = Ml[b2 * 2 + 1];
  float M = fmaxf(m1, m2);
  float w1 = __expf(m1 - M), w2 = __expf(m2 - M);
  float inv = 1.0f / (l1 * w1 + l2 * w2);
  float4 o1 = *reinterpret_cast<const float4*>(Opart + b1 * HD + dq);
  float4 o2 = *reinterpret_cast<const float4*>(Opart + b2 * HD + dq);
  bf16 o[4] = {__float2bfloat16((o1.x * w1 + o2.x * w2) * inv),
               __float2bfloat16((o1.y * w1 + o2.y * w2) * inv),
               __float2bfloat16((o1.z * w1 + o2.z * w2) * inv),
               __float2bfloat16((o1.w * w1 + o2.w * w2) * inv)};
  *reinterpret_cast<short4*>(AO + (size_t)(1024 + row) * HID + H * HD + dq) =
      *reinterpret_cast<const short4*>(o);
}

extern "C" void kernel_launch(void* const* d_in, const int* in_sizes, int n_in,
                              void* d_out, int out_size, void* d_ws, size_t ws_size,
                              hipStream_t stream) {
  const float* hidden = (const float*)d_in[0];
  const float* Wq = (const float*)d_in[2];
  const float* bq = (const float*)d_in[3];
  const float* Wk = (const float*)d_in[4];
  const float* bk = (const float*)d_in[5];
  const float* Wv = (const float*)d_in[6];
  const float* bv = (const float*)d_in[7];
  const float* Wo = (const float*)d_in[8];
  float* out = (float*)d_out;

  // workspace map (168 MiB):
  char* ws = (char*)d_ws;
  bf16*  Wqkvt = (bf16*)(ws + (size_t)0 * MiB);    // 48 MiB  [Q|K|V]^T bf16
  bf16*  Xb    = (bf16*)(ws + (size_t)48 * MiB);   // 16 MiB
  float* Cqkv  = (float*)(ws + (size_t)64 * MiB);  // 48 MiB  fp32 QKV out
  bf16*  Wot   = (bf16*)(ws + (size_t)112 * MiB);  // 32 MiB
  bf16*  Qb    = (bf16*)(ws + (size_t)144 * MiB);  // 16 MiB
  bf16*  Kb    = (bf16*)(ws + (size_t)160 * MiB);  // 4 MiB
  bf16*  Vt    = (bf16*)(ws + (size_t)164 * MiB);  // 4 MiB
  // stream-ordered aliases:
  float* bqkv  = (float*)Qb;                        // consumed by GEMM, then rope overwrites
  bf16*  AO    = (bf16*)Cqkv;                       // Cqkv dead after rope/V-transpose
  float* Opart = (float*)Wqkvt;                     // Wqkvt dead after QKV GEMM
  float* Ml    = (float*)(ws + (size_t)32 * MiB);
  float* P0    = (float*)Wqkvt;                     // Opart dead after merge
  float* P1    = (float*)(ws + (size_t)80 * MiB);   // dead Cqkv beyond AO

  cvt_kernel<<<(SEQ * HID) / 1024, 256, 0, stream>>>(hidden, Xb, SEQ * HID);
  concat_bias_kernel<<<QKVN / 256, 256, 0, stream>>>(bq, bk, bv, bqkv);
  transpose_all_kernel<<<40960, dim3(32, 8), 0, stream>>>(Wq, Wk, Wv, Wo, Wqkvt, Wot);

  // QKV GEMM (256^2 8-phase): Cqkv = Xb * Wqkvt^T + bqkv
  gemm256_kernel<<<dim3(QKVN / 256, SEQ / 256, 1), 512, 0, stream>>>(
      Xb, Wqkvt, bqkv, Cqkv, nullptr, QKVN, HID, HID);

  rope_cvt_kernel<<<(SEQ * NH * 64) / 256, 256, 0, stream>>>(Cqkv, Qb, NH, 5, QKVN);
  rope_cvt_kernel<<<(SEQ * NKV * 64) / 256, 256, 0, stream>>>(Cqkv + HID, Kb, NKV, 3, QKVN);
  transpose_cvt_kernel<<<dim3(KVDIM / 32, SEQ / 32), dim3(32, 8), 0, stream>>>(
      Cqkv + HID + KVDIM, Vt, QKVN, SEQ);

  attn_kernel<<<1536, 256, 0, stream>>>(Qb, Kb, Vt, AO, Opart, Ml);
  merge_kernel<<<(NH * 1024 * 32) / 256, 256, 0, stream>>>(Opart, Ml, AO);

  // Wo GEMM (256^2 8-phase), split-K=2: partials P0/P1, then reduce
  gemm256_kernel<<<dim3(HID / 256, SEQ / 256, 2), 512, 0, stream>>>(
      AO, Wot, nullptr, P0, P1, HID, 2048, HID);
  reduce_kernel<<<(SEQ * HID) / 1024, 256, 0, stream>>>(P0, P1, out, SEQ * HID);
}

// Round 9
// 360.007 us; speedup vs baseline: 1.1910x; 1.0549x over previous
//
#include <hip/hip_runtime.h>
#include <hip/hip_bf16.h>

typedef __hip_bfloat16 bf16;
typedef __attribute__((ext_vector_type(8))) __bf16 bf16x8;
typedef __attribute__((ext_vector_type(4))) float f32x4;

#define SEQ 2048
#define HID 4096
#define NH 32
#define NKV 8
#define HD 128
#define KVDIM 1024
#define QKVN 6144

#define MiB (1024 * 1024)

__device__ __forceinline__ void gl_lds16(const void* g, void* lds) {
  __builtin_amdgcn_global_load_lds((const __attribute__((address_space(1))) void*)g,
                                   (__attribute__((address_space(3))) void*)lds,
                                   16, 0, 0);
}

// ---------------- elementwise fp32 -> bf16 ----------------
__global__ void cvt_kernel(const float* __restrict__ in, bf16* __restrict__ out, int n) {
  int i = (blockIdx.x * blockDim.x + threadIdx.x) * 4;
  if (i >= n) return;
  float4 v = *reinterpret_cast<const float4*>(in + i);
  bf16 o[4] = {__float2bfloat16(v.x), __float2bfloat16(v.y),
               __float2bfloat16(v.z), __float2bfloat16(v.w)};
  *reinterpret_cast<short4*>(out + i) = *reinterpret_cast<const short4*>(o);
}

// ---------------- bias concat [4096|1024|1024] ----------------
__global__ void concat_bias_kernel(const float* __restrict__ bq, const float* __restrict__ bk,
                                   const float* __restrict__ bv, float* __restrict__ o) {
  int i = blockIdx.x * blockDim.x + threadIdx.x;
  if (i >= QKVN) return;
  o[i] = (i < HID) ? bq[i] : (i < HID + KVDIM ? bk[i - HID] : bv[i - HID - KVDIM]);
}

// ---------------- merged 4-way weight transpose fp32[HID][C] -> bf16[C][HID] ----------------
__global__ void transpose_all_kernel(const float* __restrict__ Wq, const float* __restrict__ Wk,
                                     const float* __restrict__ Wv, const float* __restrict__ Wo,
                                     bf16* __restrict__ Wqkvt, bf16* __restrict__ Wot) {
  __shared__ float tile[32][33];
  int t = blockIdx.x;
  const float* in;
  bf16* out;
  int si, xt, yt;
  if (t < 16384)      { in = Wq; out = Wqkvt;                           si = HID;   xt = t & 127; yt = t >> 7; }
  else if (t < 20480) { t -= 16384; in = Wk; out = Wqkvt + (size_t)HID * HID;           si = KVDIM; xt = t & 31; yt = t >> 5; }
  else if (t < 24576) { t -= 20480; in = Wv; out = Wqkvt + (size_t)(HID + KVDIM) * HID; si = KVDIM; xt = t & 31; yt = t >> 5; }
  else                { t -= 24576; in = Wo; out = Wot;                 si = HID;   xt = t & 127; yt = t >> 7; }
  int c0 = xt * 32, r0 = yt * 32;
  int tx = threadIdx.x, ty = threadIdx.y;
#pragma unroll
  for (int i = 0; i < 32; i += 8)
    tile[ty + i][tx] = in[(size_t)(r0 + ty + i) * si + (c0 + tx)];
  __syncthreads();
#pragma unroll
  for (int i = 0; i < 32; i += 8)
    out[(size_t)(c0 + ty + i) * HID + (r0 + tx)] = __float2bfloat16(tile[tx][ty + i]);
}

// ---------------- tiled transpose fp32[R][C](stride si) -> bf16[C][R](stride so) ----------------
__global__ void transpose_cvt_kernel(const float* __restrict__ in, bf16* __restrict__ out,
                                     int si, int so) {
  __shared__ float tile[32][33];
  int c0 = blockIdx.x * 32, r0 = blockIdx.y * 32;
  int tx = threadIdx.x, ty = threadIdx.y;
#pragma unroll
  for (int i = 0; i < 32; i += 8)
    tile[ty + i][tx] = in[(size_t)(r0 + ty + i) * si + (c0 + tx)];
  __syncthreads();
#pragma unroll
  for (int i = 0; i < 32; i += 8)
    out[(size_t)(c0 + ty + i) * so + (r0 + tx)] = __float2bfloat16(tile[tx][ty + i]);
}

// ---------------- RoPE fp32(stride si) -> bf16 (pos = row index) ----------------
__global__ void rope_cvt_kernel(const float* __restrict__ in, bf16* __restrict__ out,
                                int nheads, int hshift, int si) {
  int idx = blockIdx.x * blockDim.x + threadIdx.x;
  int i = idx & 63;
  int h = (idx >> 6) & (nheads - 1);
  int s = idx >> (6 + hshift);
  if (s >= SEQ) return;
  float inv = __expf(-(float)i * 0.14391156831212787f);  // ln(10000)/64
  float ang = (float)s * inv;
  float sn, cs;
  __sincosf(ang, &sn, &cs);
  size_t bi = (size_t)s * si + (size_t)h * HD + i;
  size_t bo = (size_t)s * ((size_t)nheads * HD) + (size_t)h * HD + i;
  float x1 = in[bi], x2 = in[bi + 64];
  out[bo]      = __float2bfloat16(x1 * cs - x2 * sn);
  out[bo + 64] = __float2bfloat16(x2 * cs + x1 * sn);
}

// ---------------- 256x256 8-phase GEMM (unchanged from R8) ----------------
#define BARRIER() __builtin_amdgcn_s_barrier()
#define LGKM0()                                          \
  {                                                      \
    asm volatile("s_waitcnt lgkmcnt(0)" ::: "memory");   \
    __builtin_amdgcn_sched_barrier(0);                   \
  }
#define MFMA_ACC(d, x, y) d = __builtin_amdgcn_mfma_f32_16x16x32_bf16(x, y, d, 0, 0, 0)

__global__ __launch_bounds__(512, 2) void gemm256_kernel(
    const bf16* __restrict__ A, const bf16* __restrict__ Bt,
    const float* __restrict__ bias, float* __restrict__ C0, float* __restrict__ C1,
    int N, int Ksub, int lda) {
  __shared__ bf16 lds[2][4][128 * 64];  // [buf][A0,A1,B0,B1]
  const int tid = threadIdx.x;
  const int lane = tid & 63;
  const int w = tid >> 6;
  const int wr = w >> 2, wc = w & 3;
  const int m0 = blockIdx.y * 256;
  const int n0 = blockIdx.x * 256;
  const int bz = blockIdx.z;
  const bf16* Ab = A + (size_t)bz * Ksub;
  const bf16* Btb = Bt + (size_t)bz * Ksub;
  float* Cb = bz ? C1 : C0;
  const int nt = Ksub >> 6;

#define STAGE(buf, half, t)                                                     \
  {                                                                             \
    const bf16* _s = ((half) < 2) ? Ab : Btb;                                   \
    int _g0 = (((half) < 2) ? m0 : n0) + ((half) & 1) * 128;                    \
    _Pragma("unroll")                                                           \
    for (int _it = 0; _it < 2; ++_it) {                                         \
      int _row = w * 16 + _it * 8 + (lane >> 3);                                \
      int _ch = (lane & 7) ^ (_row & 7);                                        \
      gl_lds16(_s + (size_t)(_g0 + _row) * lda + (size_t)(t) * 64 + _ch * 8,    \
               &lds[buf][half][(w * 16 + _it * 8) * 64]);                       \
    }                                                                           \
  }

  auto rdA = [&](int cur, int mi, int ks) {
    int rr = mi * 16 + (lane & 15);
    int byt = rr * 128 + (((ks * 32 + (lane >> 4) * 8) * 2) ^ ((rr & 7) << 4));
    return *reinterpret_cast<const bf16x8*>(
        reinterpret_cast<const char*>(&lds[cur][wr][0]) + byt);
  };
  auto rdB = [&](int cur, int ni, int ks) {
    int rr = (wc & 1) * 64 + ni * 16 + (lane & 15);
    int byt = rr * 128 + (((ks * 32 + (lane >> 4) * 8) * 2) ^ ((rr & 7) << 4));
    return *reinterpret_cast<const bf16x8*>(
        reinterpret_cast<const char*>(&lds[cur][2 + (wc >> 1)][0]) + byt);
  };

  f32x4 acc[8][4];
  const f32x4 z = {0.f, 0.f, 0.f, 0.f};
#pragma unroll
  for (int i = 0; i < 8; ++i)
#pragma unroll
    for (int j = 0; j < 4; ++j) acc[i][j] = z;

  STAGE(0, 0, 0); STAGE(0, 1, 0); STAGE(0, 2, 0); STAGE(0, 3, 0);
  STAGE(1, 2, 1); STAGE(1, 3, 1); STAGE(1, 0, 1);
  asm volatile("s_waitcnt vmcnt(6)" ::: "memory");
  BARRIER();

  bf16x8 a[4][2], b[4][2];
  int cur = 0;
  for (int t = 0; t < nt; ++t, cur ^= 1) {
#pragma unroll
    for (int mi = 0; mi < 4; ++mi) { a[mi][0] = rdA(cur, mi, 0); a[mi][1] = rdA(cur, mi, 1); }
#pragma unroll
    for (int ni = 0; ni < 2; ++ni) { b[ni][0] = rdB(cur, ni, 0); b[ni][1] = rdB(cur, ni, 1); }
    if (t + 1 < nt) STAGE(cur ^ 1, 1, t + 1);
    BARRIER();
    LGKM0();
    __builtin_amdgcn_s_setprio(1);
#pragma unroll
    for (int mi = 0; mi < 4; ++mi)
#pragma unroll
      for (int ni = 0; ni < 2; ++ni) {
        MFMA_ACC(acc[mi][ni], a[mi][0], b[ni][0]);
        MFMA_ACC(acc[mi][ni], a[mi][1], b[ni][1]);
      }
    __builtin_amdgcn_s_setprio(0);
    BARRIER();
#pragma unroll
    for (int ni = 2; ni < 4; ++ni) { b[ni][0] = rdB(cur, ni, 0); b[ni][1] = rdB(cur, ni, 1); }
    BARRIER();
    LGKM0();
    __builtin_amdgcn_s_setprio(1);
#pragma unroll
    for (int mi = 0; mi < 4; ++mi)
#pragma unroll
      for (int ni = 2; ni < 4; ++ni) {
        MFMA_ACC(acc[mi][ni], a[mi][0], b[ni][0]);
        MFMA_ACC(acc[mi][ni], a[mi][1], b[ni][1]);
      }
    __builtin_amdgcn_s_setprio(0);
    BARRIER();
#pragma unroll
    for (int mi = 0; mi < 4; ++mi) { a[mi][0] = rdA(cur, mi + 4, 0); a[mi][1] = rdA(cur, mi + 4, 1); }
    if (t + 2 < nt) { STAGE(cur, 2, t + 2); STAGE(cur, 3, t + 2); }
    BARRIER();
    LGKM0();
    __builtin_amdgcn_s_setprio(1);
#pragma unroll
    for (int mi = 0; mi < 4; ++mi)
#pragma unroll
      for (int ni = 2; ni < 4; ++ni) {
        MFMA_ACC(acc[mi + 4][ni], a[mi][0], b[ni][0]);
        MFMA_ACC(acc[mi + 4][ni], a[mi][1], b[ni][1]);
      }
    __builtin_amdgcn_s_setprio(0);
    BARRIER();
    if (t + 2 < nt) STAGE(cur, 0, t + 2);
    if (t + 2 < nt) {
      asm volatile("s_waitcnt vmcnt(6)" ::: "memory");
    } else if (t + 1 < nt) {
      asm volatile("s_waitcnt vmcnt(0)" ::: "memory");
    }
    BARRIER();
    __builtin_amdgcn_s_setprio(1);
#pragma unroll
    for (int mi = 0; mi < 4; ++mi)
#pragma unroll
      for (int ni = 0; ni < 2; ++ni) {
        MFMA_ACC(acc[mi + 4][ni], a[mi][0], b[ni][0]);
        MFMA_ACC(acc[mi + 4][ni], a[mi][1], b[ni][1]);
      }
    __builtin_amdgcn_s_setprio(0);
    BARRIER();
  }

#pragma unroll
  for (int ni = 0; ni < 4; ++ni) {
    int col = n0 + wc * 64 + ni * 16 + (lane & 15);
    float bv = bias ? bias[col] : 0.0f;
#pragma unroll
    for (int mi = 0; mi < 8; ++mi) {
      int rbase = m0 + wr * 128 + mi * 16 + (lane >> 4) * 4;
#pragma unroll
      for (int r = 0; r < 4; ++r)
        Cb[(size_t)(rbase + r) * N + col] = acc[mi][ni][r] + bv;
    }
  }
#undef STAGE
}

// ---------------- reduce: out = P0 + P1 ----------------
__global__ void reduce_kernel(const float* __restrict__ P0, const float* __restrict__ P1,
                              float* __restrict__ out, int n) {
  int i = (blockIdx.x * blockDim.x + threadIdx.x) * 4;
  if (i >= n) return;
  float4 a = *reinterpret_cast<const float4*>(P0 + i);
  float4 b = *reinterpret_cast<const float4*>(P1 + i);
  float4 o = {a.x + b.x, a.y + b.y, a.z + b.z, a.w + b.w};
  *reinterpret_cast<float4*>(out + i) = o;
}

// ---------------- flash attention: swapped QK^T (S^T frags), per-lane softmax ----------------
// Per wave: 16 q-rows. QK^T computed as mfma(K,Q) so lane holds P[q = lane&15]
// [kv = j*16 + (lane>>4)*4 + r] -> softmax is in-lane + 2 shfl_xor; P written as
// 4x ds_write_b64 into per-wave [q][kv] swizzled buffer (PV read layout unchanged).
__global__ __launch_bounds__(256) void attn_kernel(
    const bf16* __restrict__ Q,   // [SEQ][HID]
    const bf16* __restrict__ Kb,  // [SEQ][KVDIM]
    const bf16* __restrict__ Vt,  // [KVDIM][SEQ]
    bf16* __restrict__ AO,        // [SEQ][HID]
    float* __restrict__ Opart,    // [2][NH][1024][HD]
    float* __restrict__ Ml) {     // [2][NH][1024][2]
  __shared__ bf16 Ks[64 * 128];
  __shared__ bf16 Vs[128 * 64];
  __shared__ bf16 Ps[4][16 * 64];
  const int tid = threadIdx.x, lane = tid & 63, w = tid >> 6;
  const int b = blockIdx.x;
  const int H = b & 31;
  const int tt = b >> 5;
  int qb, lo, hi, half;
  bool split;
  if (tt < 32) {
    qb = 16 + ((31 - tt) >> 1);
    half = tt & 1;
    int n = qb + 1, mid = n >> 1;
    lo = half ? mid : 0;
    hi = half ? n : mid;
    split = true;
  } else {
    qb = 47 - tt;
    half = 0;
    lo = 0;
    hi = qb + 1;
    split = false;
  }
  const int kvh = H >> 2;
  const int qw = qb * 64 + w * 16;
  const int hig = lane >> 4;     // 0..3
  const int q_loc = lane & 15;
  const int qa = qw + q_loc;     // this lane's q-row (softmax ownership)

  bf16x8 aq[4];
#pragma unroll
  for (int kd = 0; kd < 4; ++kd) {
    int row = qw + q_loc;
    int d = kd * 32 + hig * 8;
    aq[kd] = *reinterpret_cast<const bf16x8*>(Q + (size_t)row * HID + H * HD + d);
  }

  float m_run = -1e30f, l_run = 0.0f;  // per-lane, for q = qa
  f32x4 o[8];
  const f32x4 z = {0.f, 0.f, 0.f, 0.f};
#pragma unroll
  for (int dt = 0; dt < 8; ++dt) o[dt] = z;

  const float scale = 0.08838834764831845f;

  for (int t = lo; t < hi; ++t) {
    int kvbase = t * 64;
#pragma unroll
    for (int it = 0; it < 4; ++it) {
      int c = w * 4 + it;
      int row = c * 4 + (lane >> 4);
      int sb = ((lane & 15) * 16) ^ ((row & 7) << 4);
      gl_lds16(Kb + (size_t)(kvbase + row) * KVDIM + kvh * HD + (sb >> 1), &Ks[c * 512]);
    }
#pragma unroll
    for (int it = 0; it < 4; ++it) {
      int c = w * 4 + it;
      int row = c * 8 + (lane >> 3);
      int sb = ((lane & 7) * 16) ^ ((row & 7) << 4);
      gl_lds16(Vt + (size_t)(kvh * HD + row) * SEQ + kvbase + (sb >> 1), &Vs[c * 512]);
    }
    __syncthreads();

    // S^T = (Q K^T)^T via mfma(K, Q): row=kv_local, col=q_local
    f32x4 sf[4];
#pragma unroll
    for (int j = 0; j < 4; ++j) sf[j] = z;
#pragma unroll
    for (int j = 0; j < 4; ++j) {
#pragma unroll
      for (int kd = 0; kd < 4; ++kd) {
        int r = j * 16 + q_loc;
        int byt = r * 256 + (((kd * 32 + hig * 8) * 2) ^ ((r & 7) << 4));
        bf16x8 kfr = *reinterpret_cast<const bf16x8*>(reinterpret_cast<const char*>(Ks) + byt);
        sf[j] = __builtin_amdgcn_mfma_f32_16x16x32_bf16(kfr, aq[kd], sf[j], 0, 0, 0);
      }
    }

    // lane holds 16 P-values for its q-row: kv = kvbase + j*16 + hig*4 + r
    float vals[4][4];
    bool diag = (t == qb);
#pragma unroll
    for (int j = 0; j < 4; ++j)
#pragma unroll
      for (int r = 0; r < 4; ++r) {
        float v = sf[j][r] * scale;
        if (diag) {
          int ka = kvbase + j * 16 + hig * 4 + r;
          if (ka > qa) v = -1e30f;
        }
        vals[j][r] = v;
      }

    float m01 = fmaxf(fmaxf(vals[0][0], vals[0][1]), fmaxf(vals[0][2], vals[0][3]));
    float m23 = fmaxf(fmaxf(vals[1][0], vals[1][1]), fmaxf(vals[1][2], vals[1][3]));
    float m45 = fmaxf(fmaxf(vals[2][0], vals[2][1]), fmaxf(vals[2][2], vals[2][3]));
    float m67 = fmaxf(fmaxf(vals[3][0], vals[3][1]), fmaxf(vals[3][2], vals[3][3]));
    float m = fmaxf(fmaxf(m01, m23), fmaxf(m45, m67));
    m = fmaxf(m, __shfl_xor(m, 16));
    m = fmaxf(m, __shfl_xor(m, 32));
    float mn = fmaxf(m_run, m);
    float alpha = __expf(m_run - mn);
    m_run = mn;

    float p[4][4];
    float rs = 0.0f;
#pragma unroll
    for (int j = 0; j < 4; ++j)
#pragma unroll
      for (int r = 0; r < 4; ++r) {
        p[j][r] = __expf(vals[j][r] - mn);
        rs += p[j][r];
      }
    rs += __shfl_xor(rs, 16);
    rs += __shfl_xor(rs, 32);
    l_run = l_run * alpha + rs;

    // P write: row q_loc, cols kv (4 bf16 per j as one b64)
#pragma unroll
    for (int j = 0; j < 4; ++j) {
      bf16 tmp[4] = {__float2bfloat16(p[j][0]), __float2bfloat16(p[j][1]),
                     __float2bfloat16(p[j][2]), __float2bfloat16(p[j][3])};
      int coff = (j * 16 + hig * 4) * 2;
      int byt = q_loc * 128 + (coff ^ ((q_loc & 7) << 4));
      *reinterpret_cast<uint2*>(reinterpret_cast<char*>(&Ps[w][0]) + byt) =
          *reinterpret_cast<const uint2*>(tmp);
    }

    // rescale o by alpha of o-row q' = qw + hig*4 + r
#pragma unroll
    for (int r = 0; r < 4; ++r) {
      float alr = __shfl(alpha, hig * 4 + r);
#pragma unroll
      for (int dt = 0; dt < 8; ++dt) o[dt][r] *= alr;
    }

    bf16x8 pa[2];
#pragma unroll
    for (int ks = 0; ks < 2; ++ks) {
      int byt = q_loc * 128 + (((ks * 32 + hig * 8) * 2) ^ ((q_loc & 7) << 4));
      pa[ks] = *reinterpret_cast<const bf16x8*>(reinterpret_cast<const char*>(&Ps[w][0]) + byt);
    }
#pragma unroll
    for (int dt = 0; dt < 8; ++dt)
#pragma unroll
      for (int ks = 0; ks < 2; ++ks) {
        int vrow = dt * 16 + q_loc;
        int byt = vrow * 128 + (((ks * 32 + hig * 8) * 2) ^ ((vrow & 7) << 4));
        bf16x8 vb = *reinterpret_cast<const bf16x8*>(reinterpret_cast<const char*>(Vs) + byt);
        o[dt] = __builtin_amdgcn_mfma_f32_16x16x32_bf16(pa[ks], vb, o[dt], 0, 0, 0);
      }
    __syncthreads();
  }

  if (!split) {
#pragma unroll
    for (int r = 0; r < 4; ++r) {
      float li = __shfl(l_run, hig * 4 + r);
      float linv = 1.0f / li;
#pragma unroll
      for (int dt = 0; dt < 8; ++dt) {
        int qrow = qw + hig * 4 + r;
        int d = dt * 16 + q_loc;
        AO[(size_t)qrow * HID + H * HD + d] = __float2bfloat16(o[dt][r] * linv);
      }
    }
  } else {
    size_t pbase = ((size_t)(half * NH + H) * 1024);
#pragma unroll
    for (int dt = 0; dt < 8; ++dt)
#pragma unroll
      for (int r = 0; r < 4; ++r) {
        int qrow = qw + hig * 4 + r;
        int d = dt * 16 + q_loc;
        Opart[(pbase + (qrow - 1024)) * HD + d] = o[dt][r];
      }
    if (lane < 16) {
      Ml[(pbase + (qa - 1024)) * 2 + 0] = m_run;
      Ml[(pbase + (qa - 1024)) * 2 + 1] = l_run;
    }
  }
}

// ---------------- merge split-attention partials ----------------
__global__ __launch_bounds__(256) void merge_kernel(
    const float* __restrict__ Opart, const float* __restrict__ Ml,
    bf16* __restrict__ AO) {
  int i = blockIdx.x * 256 + threadIdx.x;
  int dq = (i & 31) << 2;
  int row = (i >> 5) & 1023;
  int H = i >> 15;
  size_t b1 = (size_t)H * 1024 + row;
  size_t b2 = (size_t)(NH + H) * 1024 + row;
  float m1 = Ml[b1 * 2], l1 = Ml[b1 * 2 + 1];
  float m2 = Ml[b2 * 2], l2 = Ml[b2 * 2 + 1];
  float M = fmaxf(m1, m2);
  float w1 = __expf(m1 - M), w2 = __expf(m2 - M);
  float inv = 1.0f / (l1 * w1 + l2 * w2);
  float4 o1 = *reinterpret_cast<const float4*>(Opart + b1 * HD + dq);
  float4 o2 = *reinterpret_cast<const float4*>(Opart + b2 * HD + dq);
  bf16 o[4] = {__float2bfloat16((o1.x * w1 + o2.x * w2) * inv),
               __float2bfloat16((o1.y * w1 + o2.y * w2) * inv),
               __float2bfloat16((o1.z * w1 + o2.z * w2) * inv),
               __float2bfloat16((o1.w * w1 + o2.w * w2) * inv)};
  *reinterpret_cast<short4*>(AO + (size_t)(1024 + row) * HID + H * HD + dq) =
      *reinterpret_cast<const short4*>(o);
}

extern "C" void kernel_launch(void* const* d_in, const int* in_sizes, int n_in,
                              void* d_out, int out_size, void* d_ws, size_t ws_size,
                              hipStream_t stream) {
  const float* hidden = (const float*)d_in[0];
  const float* Wq = (const float*)d_in[2];
  const float* bq = (const float*)d_in[3];
  const float* Wk = (const float*)d_in[4];
  const float* bk = (const float*)d_in[5];
  const float* Wv = (const float*)d_in[6];
  const float* bv = (const float*)d_in[7];
  const float* Wo = (const float*)d_in[8];
  float* out = (float*)d_out;

  // workspace map (168 MiB):
  char* ws = (char*)d_ws;
  bf16*  Wqkvt = (bf16*)(ws + (size_t)0 * MiB);    // 48 MiB  [Q|K|V]^T bf16
  bf16*  Xb    = (bf16*)(ws + (size_t)48 * MiB);   // 16 MiB
  float* Cqkv  = (float*)(ws + (size_t)64 * MiB);  // 48 MiB  fp32 QKV out
  bf16*  Wot   = (bf16*)(ws + (size_t)112 * MiB);  // 32 MiB
  bf16*  Qb    = (bf16*)(ws + (size_t)144 * MiB);  // 16 MiB
  bf16*  Kb    = (bf16*)(ws + (size_t)160 * MiB);  // 4 MiB
  bf16*  Vt    = (bf16*)(ws + (size_t)164 * MiB);  // 4 MiB
  // stream-ordered aliases:
  float* bqkv  = (float*)Qb;                        // consumed by GEMM, then rope overwrites
  bf16*  AO    = (bf16*)Cqkv;                       // Cqkv dead after rope/V-transpose
  float* Opart = (float*)Wqkvt;                     // Wqkvt dead after QKV GEMM
  float* Ml    = (float*)(ws + (size_t)32 * MiB);
  float* P0    = (float*)Wqkvt;                     // Opart dead after merge
  float* P1    = (float*)(ws + (size_t)80 * MiB);   // dead Cqkv beyond AO

  cvt_kernel<<<(SEQ * HID) / 1024, 256, 0, stream>>>(hidden, Xb, SEQ * HID);
  concat_bias_kernel<<<QKVN / 256, 256, 0, stream>>>(bq, bk, bv, bqkv);
  transpose_all_kernel<<<40960, dim3(32, 8), 0, stream>>>(Wq, Wk, Wv, Wo, Wqkvt, Wot);

  // QKV GEMM (256^2 8-phase): Cqkv = Xb * Wqkvt^T + bqkv
  gemm256_kernel<<<dim3(QKVN / 256, SEQ / 256, 1), 512, 0, stream>>>(
      Xb, Wqkvt, bqkv, Cqkv, nullptr, QKVN, HID, HID);

  rope_cvt_kernel<<<(SEQ * NH * 64) / 256, 256, 0, stream>>>(Cqkv, Qb, NH, 5, QKVN);
  rope_cvt_kernel<<<(SEQ * NKV * 64) / 256, 256, 0, stream>>>(Cqkv + HID, Kb, NKV, 3, QKVN);
  transpose_cvt_kernel<<<dim3(KVDIM / 32, SEQ / 32), dim3(32, 8), 0, stream>>>(
      Cqkv + HID + KVDIM, Vt, QKVN, SEQ);

  attn_kernel<<<1536, 256, 0, stream>>>(Qb, Kb, Vt, AO, Opart, Ml);
  merge_kernel<<<(NH * 1024 * 32) / 256, 256, 0, stream>>>(Opart, Ml, AO);

  // Wo GEMM (256^2 8-phase), split-K=2: partials P0/P1, then reduce
  gemm256_kernel<<<dim3(HID / 256, SEQ / 256, 2), 512, 0, stream>>>(
      AO, Wot, nullptr, P0, P1, HID, 2048, HID);
  reduce_kernel<<<(SEQ * HID) / 1024, 256, 0, stream>>>(P0, P1, out, SEQ * HID);
}

// Round 10
// 358.044 us; speedup vs baseline: 1.1975x; 1.0055x over previous
//
#include <hip/hip_runtime.h>
#include <hip/hip_bf16.h>

typedef __hip_bfloat16 bf16;
typedef __attribute__((ext_vector_type(8))) __bf16 bf16x8;
typedef __attribute__((ext_vector_type(4))) float f32x4;

#define SEQ 2048
#define HID 4096
#define NH 32
#define NKV 8
#define HD 128
#define KVDIM 1024
#define QKVN 6144

#define MiB (1024 * 1024)

__device__ __forceinline__ void gl_lds16(const void* g, void* lds) {
  __builtin_amdgcn_global_load_lds((const __attribute__((address_space(1))) void*)g,
                                   (__attribute__((address_space(3))) void*)lds,
                                   16, 0, 0);
}

__device__ __forceinline__ float unplo(unsigned u) { return __uint_as_float(u << 16); }
__device__ __forceinline__ float unphi(unsigned u) { return __uint_as_float(u & 0xffff0000u); }
__device__ __forceinline__ unsigned packbf(float a, float b) {
  bf16 t[2] = {__float2bfloat16(a), __float2bfloat16(b)};
  return *reinterpret_cast<unsigned*>(t);
}

// ---------------- elementwise fp32 -> bf16 ----------------
__global__ void cvt_kernel(const float* __restrict__ in, bf16* __restrict__ out, int n) {
  int i = (blockIdx.x * blockDim.x + threadIdx.x) * 4;
  if (i >= n) return;
  float4 v = *reinterpret_cast<const float4*>(in + i);
  bf16 o[4] = {__float2bfloat16(v.x), __float2bfloat16(v.y),
               __float2bfloat16(v.z), __float2bfloat16(v.w)};
  *reinterpret_cast<short4*>(out + i) = *reinterpret_cast<const short4*>(o);
}

// ---------------- bias concat [4096|1024|1024] ----------------
__global__ void concat_bias_kernel(const float* __restrict__ bq, const float* __restrict__ bk,
                                   const float* __restrict__ bv, float* __restrict__ o) {
  int i = blockIdx.x * blockDim.x + threadIdx.x;
  if (i >= QKVN) return;
  o[i] = (i < HID) ? bq[i] : (i < HID + KVDIM ? bk[i - HID] : bv[i - HID - KVDIM]);
}

// ---------------- QKV weight transpose fp32[HID][C] -> bf16[C][HID] ----------------
// tiles: [0,16384) Wq, [16384,20480) Wk, [20480,24576) Wv
__global__ void transpose_qkvw_kernel(const float* __restrict__ Wq, const float* __restrict__ Wk,
                                      const float* __restrict__ Wv, bf16* __restrict__ Wqkvt) {
  __shared__ float tile[32][33];
  int t = blockIdx.x;
  const float* in;
  bf16* out;
  int si, xt, yt;
  if (t < 16384)      { in = Wq; out = Wqkvt;                           si = HID;   xt = t & 127; yt = t >> 7; }
  else if (t < 20480) { t -= 16384; in = Wk; out = Wqkvt + (size_t)HID * HID;           si = KVDIM; xt = t & 31; yt = t >> 5; }
  else                { t -= 20480; in = Wv; out = Wqkvt + (size_t)(HID + KVDIM) * HID; si = KVDIM; xt = t & 31; yt = t >> 5; }
  int c0 = xt * 32, r0 = yt * 32;
  int tx = threadIdx.x, ty = threadIdx.y;
#pragma unroll
  for (int i = 0; i < 32; i += 8)
    tile[ty + i][tx] = in[(size_t)(r0 + ty + i) * si + (c0 + tx)];
  __syncthreads();
#pragma unroll
  for (int i = 0; i < 32; i += 8)
    out[(size_t)(c0 + ty + i) * HID + (r0 + tx)] = __float2bfloat16(tile[tx][ty + i]);
}

// ---------------- fused post-QKV: rope Q, rope K, V transpose (bf16 in) ----------------
// blocks [0,8192) rope-Q, [8192,10240) rope-K, [10240,12288) V-transpose
__global__ void postqkv_kernel(const bf16* __restrict__ Ch, bf16* __restrict__ Qb,
                               bf16* __restrict__ Kb, bf16* __restrict__ Vt) {
  __shared__ float tile[32][33];
  int b = blockIdx.x;
  int tid = threadIdx.x;
  if (b < 10240) {
    bool isQ = (b < 8192);
    int idx = (isQ ? b : b - 8192) * 256 + tid;
    int j = idx & 31;                       // pair index: i = 2j, 2j+1
    int h = (idx >> 5) & (isQ ? 31 : 7);
    int s = idx >> (isQ ? 10 : 8);
    size_t bi = (size_t)s * QKVN + (isQ ? 0 : HID) + h * HD;
    unsigned u1 = *reinterpret_cast<const unsigned*>(Ch + bi + 2 * j);
    unsigned u2 = *reinterpret_cast<const unsigned*>(Ch + bi + 64 + 2 * j);
    float x1a = unplo(u1), x1b = unphi(u1);
    float x2a = unplo(u2), x2b = unphi(u2);
    float inv0 = __expf(-(float)(2 * j) * 0.14391156831212787f);
    float inv1 = __expf(-(float)(2 * j + 1) * 0.14391156831212787f);
    float sn0, cs0, sn1, cs1;
    __sincosf((float)s * inv0, &sn0, &cs0);
    __sincosf((float)s * inv1, &sn1, &cs1);
    size_t bo = (size_t)s * (isQ ? HID : KVDIM) + h * HD;
    bf16* Ob = isQ ? Qb : Kb;
    *reinterpret_cast<unsigned*>(Ob + bo + 2 * j) =
        packbf(x1a * cs0 - x2a * sn0, x1b * cs1 - x2b * sn1);
    *reinterpret_cast<unsigned*>(Ob + bo + 64 + 2 * j) =
        packbf(x2a * cs0 + x1a * sn0, x2b * cs1 + x1b * sn1);
  } else {
    int t = b - 10240;                      // V transpose: 32 col-tiles x 64 row-tiles
    int xt = t & 31, yt = t >> 5;
    int tx = tid & 31, ty = tid >> 5;
#pragma unroll
    for (int i = 0; i < 32; i += 8)
      tile[ty + i][tx] = __bfloat162float(Ch[(size_t)(yt * 32 + ty + i) * QKVN + (HID + KVDIM) + xt * 32 + tx]);
    __syncthreads();
#pragma unroll
    for (int i = 0; i < 32; i += 8)
      Vt[(size_t)(xt * 32 + ty + i) * SEQ + (yt * 32 + tx)] = __float2bfloat16(tile[tx][ty + i]);
  }
}

// ---------------- 256x256 8-phase GEMM ----------------
// mode 1 (QKV): 1-D grid 256; b<192: GEMM tile (x=b%24,y=b/24), bf16 out to Ch;
//               b>=192: Wo fp32->bf16 transpose worker (64 blocks x 256 tiles).
// mode 0 (Wo):  1-D grid 256; z=b>>7, x=(b&127)&15, y=(b&127)>>4; fp32 out P0/P1.
#define BARRIER() __builtin_amdgcn_s_barrier()
#define LGKM0()                                          \
  {                                                      \
    asm volatile("s_waitcnt lgkmcnt(0)" ::: "memory");   \
    __builtin_amdgcn_sched_barrier(0);                   \
  }
#define MFMA_ACC(d, x, y) d = __builtin_amdgcn_mfma_f32_16x16x32_bf16(x, y, d, 0, 0, 0)

__global__ __launch_bounds__(512, 2) void gemm256_kernel(
    const bf16* __restrict__ A, const bf16* __restrict__ Bt,
    const float* __restrict__ bias, float* __restrict__ C0, float* __restrict__ C1,
    bf16* __restrict__ Ch, const float* __restrict__ WoSrc, bf16* __restrict__ WotDst,
    int N, int Ksub, int lda, int mode) {
  __shared__ bf16 lds[2][4][128 * 64];  // [buf][A0,A1,B0,B1]
  const int blk = blockIdx.x;
  int bx, by, bz;
  if (mode == 1) {
    if (blk >= 192) {
      // ---- Wo transpose worker: 2 x 32x32 tiles per pass, 128 passes ----
      float (*tile)[32][33] = reinterpret_cast<float(*)[32][33]>(&lds[0][0][0]);
      int k = blk - 192;
      int tid = threadIdx.x;
      int sub = tid >> 8, tx = tid & 31, ty = (tid >> 5) & 7;
      for (int p = 0; p < 128; ++p) {
        int t = k * 256 + p * 2 + sub;
        int xt = t & 127, yt = t >> 7;
#pragma unroll
        for (int i = 0; i < 32; i += 8)
          tile[sub][ty + i][tx] = WoSrc[(size_t)(yt * 32 + ty + i) * HID + xt * 32 + tx];
        __syncthreads();
#pragma unroll
        for (int i = 0; i < 32; i += 8)
          WotDst[(size_t)(xt * 32 + ty + i) * HID + (yt * 32 + tx)] =
              __float2bfloat16(tile[sub][tx][ty + i]);
        __syncthreads();
      }
      return;
    }
    bx = blk % 24; by = blk / 24; bz = 0;
  } else {
    bz = blk >> 7;
    int rem = blk & 127;
    bx = rem & 15; by = rem >> 4;
  }
  const int tid = threadIdx.x;
  const int lane = tid & 63;
  const int w = tid >> 6;
  const int wr = w >> 2, wc = w & 3;
  const int m0 = by * 256;
  const int n0 = bx * 256;
  const bf16* Ab = A + (size_t)bz * Ksub;
  const bf16* Btb = Bt + (size_t)bz * Ksub;
  const int nt = Ksub >> 6;

#define STAGE(buf, half, t)                                                     \
  {                                                                             \
    const bf16* _s = ((half) < 2) ? Ab : Btb;                                   \
    int _g0 = (((half) < 2) ? m0 : n0) + ((half) & 1) * 128;                    \
    _Pragma("unroll")                                                           \
    for (int _it = 0; _it < 2; ++_it) {                                         \
      int _row = w * 16 + _it * 8 + (lane >> 3);                                \
      int _ch = (lane & 7) ^ (_row & 7);                                        \
      gl_lds16(_s + (size_t)(_g0 + _row) * lda + (size_t)(t) * 64 + _ch * 8,    \
               &lds[buf][half][(w * 16 + _it * 8) * 64]);                       \
    }                                                                           \
  }

  auto rdA = [&](int cur, int mi, int ks) {
    int rr = mi * 16 + (lane & 15);
    int byt = rr * 128 + (((ks * 32 + (lane >> 4) * 8) * 2) ^ ((rr & 7) << 4));
    return *reinterpret_cast<const bf16x8*>(
        reinterpret_cast<const char*>(&lds[cur][wr][0]) + byt);
  };
  auto rdB = [&](int cur, int ni, int ks) {
    int rr = (wc & 1) * 64 + ni * 16 + (lane & 15);
    int byt = rr * 128 + (((ks * 32 + (lane >> 4) * 8) * 2) ^ ((rr & 7) << 4));
    return *reinterpret_cast<const bf16x8*>(
        reinterpret_cast<const char*>(&lds[cur][2 + (wc >> 1)][0]) + byt);
  };

  f32x4 acc[8][4];
  const f32x4 z = {0.f, 0.f, 0.f, 0.f};
#pragma unroll
  for (int i = 0; i < 8; ++i)
#pragma unroll
    for (int j = 0; j < 4; ++j) acc[i][j] = z;

  STAGE(0, 0, 0); STAGE(0, 1, 0); STAGE(0, 2, 0); STAGE(0, 3, 0);
  STAGE(1, 2, 1); STAGE(1, 3, 1); STAGE(1, 0, 1);
  asm volatile("s_waitcnt vmcnt(6)" ::: "memory");
  BARRIER();

  bf16x8 a[4][2], b[4][2];
  int cur = 0;
  for (int t = 0; t < nt; ++t, cur ^= 1) {
#pragma unroll
    for (int mi = 0; mi < 4; ++mi) { a[mi][0] = rdA(cur, mi, 0); a[mi][1] = rdA(cur, mi, 1); }
#pragma unroll
    for (int ni = 0; ni < 2; ++ni) { b[ni][0] = rdB(cur, ni, 0); b[ni][1] = rdB(cur, ni, 1); }
    if (t + 1 < nt) STAGE(cur ^ 1, 1, t + 1);
    BARRIER();
    LGKM0();
    __builtin_amdgcn_s_setprio(1);
#pragma unroll
    for (int mi = 0; mi < 4; ++mi)
#pragma unroll
      for (int ni = 0; ni < 2; ++ni) {
        MFMA_ACC(acc[mi][ni], a[mi][0], b[ni][0]);
        MFMA_ACC(acc[mi][ni], a[mi][1], b[ni][1]);
      }
    __builtin_amdgcn_s_setprio(0);
    BARRIER();
#pragma unroll
    for (int ni = 2; ni < 4; ++ni) { b[ni][0] = rdB(cur, ni, 0); b[ni][1] = rdB(cur, ni, 1); }
    BARRIER();
    LGKM0();
    __builtin_amdgcn_s_setprio(1);
#pragma unroll
    for (int mi = 0; mi < 4; ++mi)
#pragma unroll
      for (int ni = 2; ni < 4; ++ni) {
        MFMA_ACC(acc[mi][ni], a[mi][0], b[ni][0]);
        MFMA_ACC(acc[mi][ni], a[mi][1], b[ni][1]);
      }
    __builtin_amdgcn_s_setprio(0);
    BARRIER();
#pragma unroll
    for (int mi = 0; mi < 4; ++mi) { a[mi][0] = rdA(cur, mi + 4, 0); a[mi][1] = rdA(cur, mi + 4, 1); }
    if (t + 2 < nt) { STAGE(cur, 2, t + 2); STAGE(cur, 3, t + 2); }
    BARRIER();
    LGKM0();
    __builtin_amdgcn_s_setprio(1);
#pragma unroll
    for (int mi = 0; mi < 4; ++mi)
#pragma unroll
      for (int ni = 2; ni < 4; ++ni) {
        MFMA_ACC(acc[mi + 4][ni], a[mi][0], b[ni][0]);
        MFMA_ACC(acc[mi + 4][ni], a[mi][1], b[ni][1]);
      }
    __builtin_amdgcn_s_setprio(0);
    BARRIER();
    if (t + 2 < nt) STAGE(cur, 0, t + 2);
    if (t + 2 < nt) {
      asm volatile("s_waitcnt vmcnt(6)" ::: "memory");
    } else if (t + 1 < nt) {
      asm volatile("s_waitcnt vmcnt(0)" ::: "memory");
    }
    BARRIER();
    __builtin_amdgcn_s_setprio(1);
#pragma unroll
    for (int mi = 0; mi < 4; ++mi)
#pragma unroll
      for (int ni = 0; ni < 2; ++ni) {
        MFMA_ACC(acc[mi + 4][ni], a[mi][0], b[ni][0]);
        MFMA_ACC(acc[mi + 4][ni], a[mi][1], b[ni][1]);
      }
    __builtin_amdgcn_s_setprio(0);
    BARRIER();
  }

  if (mode == 1) {
#pragma unroll
    for (int ni = 0; ni < 4; ++ni) {
      int col = n0 + wc * 64 + ni * 16 + (lane & 15);
      float bv = bias[col];
#pragma unroll
      for (int mi = 0; mi < 8; ++mi) {
        int rbase = m0 + wr * 128 + mi * 16 + (lane >> 4) * 4;
#pragma unroll
        for (int r = 0; r < 4; ++r)
          Ch[(size_t)(rbase + r) * N + col] = __float2bfloat16(acc[mi][ni][r] + bv);
      }
    }
  } else {
    float* Cb = bz ? C1 : C0;
#pragma unroll
    for (int ni = 0; ni < 4; ++ni) {
      int col = n0 + wc * 64 + ni * 16 + (lane & 15);
#pragma unroll
      for (int mi = 0; mi < 8; ++mi) {
        int rbase = m0 + wr * 128 + mi * 16 + (lane >> 4) * 4;
#pragma unroll
        for (int r = 0; r < 4; ++r)
          Cb[(size_t)(rbase + r) * N + col] = acc[mi][ni][r];
      }
    }
  }
#undef STAGE
}

// ---------------- reduce: out = P0 + P1 ----------------
__global__ void reduce_kernel(const float* __restrict__ P0, const float* __restrict__ P1,
                              float* __restrict__ out, int n) {
  int i = (blockIdx.x * blockDim.x + threadIdx.x) * 4;
  if (i >= n) return;
  float4 a = *reinterpret_cast<const float4*>(P0 + i);
  float4 b = *reinterpret_cast<const float4*>(P1 + i);
  float4 o = {a.x + b.x, a.y + b.y, a.z + b.z, a.w + b.w};
  *reinterpret_cast<float4*>(out + i) = o;
}

// ---------------- flash attention: swapped QK^T, per-lane softmax (unchanged R9) ----------------
__global__ __launch_bounds__(256) void attn_kernel(
    const bf16* __restrict__ Q,   // [SEQ][HID]
    const bf16* __restrict__ Kb,  // [SEQ][KVDIM]
    const bf16* __restrict__ Vt,  // [KVDIM][SEQ]
    bf16* __restrict__ AO,        // [SEQ][HID]
    float* __restrict__ Opart,    // [2][NH][1024][HD]
    float* __restrict__ Ml) {     // [2][NH][1024][2]
  __shared__ bf16 Ks[64 * 128];
  __shared__ bf16 Vs[128 * 64];
  __shared__ bf16 Ps[4][16 * 64];
  const int tid = threadIdx.x, lane = tid & 63, w = tid >> 6;
  const int b = blockIdx.x;
  const int H = b & 31;
  const int tt = b >> 5;
  int qb, lo, hi, half;
  bool split;
  if (tt < 32) {
    qb = 16 + ((31 - tt) >> 1);
    half = tt & 1;
    int n = qb + 1, mid = n >> 1;
    lo = half ? mid : 0;
    hi = half ? n : mid;
    split = true;
  } else {
    qb = 47 - tt;
    half = 0;
    lo = 0;
    hi = qb + 1;
    split = false;
  }
  const int kvh = H >> 2;
  const int qw = qb * 64 + w * 16;
  const int hig = lane >> 4;
  const int q_loc = lane & 15;
  const int qa = qw + q_loc;

  bf16x8 aq[4];
#pragma unroll
  for (int kd = 0; kd < 4; ++kd) {
    int row = qw + q_loc;
    int d = kd * 32 + hig * 8;
    aq[kd] = *reinterpret_cast<const bf16x8*>(Q + (size_t)row * HID + H * HD + d);
  }

  float m_run = -1e30f, l_run = 0.0f;
  f32x4 o[8];
  const f32x4 z = {0.f, 0.f, 0.f, 0.f};
#pragma unroll
  for (int dt = 0; dt < 8; ++dt) o[dt] = z;

  const float scale = 0.08838834764831845f;

  for (int t = lo; t < hi; ++t) {
    int kvbase = t * 64;
#pragma unroll
    for (int it = 0; it < 4; ++it) {
      int c = w * 4 + it;
      int row = c * 4 + (lane >> 4);
      int sb = ((lane & 15) * 16) ^ ((row & 7) << 4);
      gl_lds16(Kb + (size_t)(kvbase + row) * KVDIM + kvh * HD + (sb >> 1), &Ks[c * 512]);
    }
#pragma unroll
    for (int it = 0; it < 4; ++it) {
      int c = w * 4 + it;
      int row = c * 8 + (lane >> 3);
      int sb = ((lane & 7) * 16) ^ ((row & 7) << 4);
      gl_lds16(Vt + (size_t)(kvh * HD + row) * SEQ + kvbase + (sb >> 1), &Vs[c * 512]);
    }
    __syncthreads();

    f32x4 sf[4];
#pragma unroll
    for (int j = 0; j < 4; ++j) sf[j] = z;
#pragma unroll
    for (int j = 0; j < 4; ++j) {
#pragma unroll
      for (int kd = 0; kd < 4; ++kd) {
        int r = j * 16 + q_loc;
        int byt = r * 256 + (((kd * 32 + hig * 8) * 2) ^ ((r & 7) << 4));
        bf16x8 kfr = *reinterpret_cast<const bf16x8*>(reinterpret_cast<const char*>(Ks) + byt);
        sf[j] = __builtin_amdgcn_mfma_f32_16x16x32_bf16(kfr, aq[kd], sf[j], 0, 0, 0);
      }
    }

    float vals[4][4];
    bool diag = (t == qb);
#pragma unroll
    for (int j = 0; j < 4; ++j)
#pragma unroll
      for (int r = 0; r < 4; ++r) {
        float v = sf[j][r] * scale;
        if (diag) {
          int ka = kvbase + j * 16 + hig * 4 + r;
          if (ka > qa) v = -1e30f;
        }
        vals[j][r] = v;
      }

    float m01 = fmaxf(fmaxf(vals[0][0], vals[0][1]), fmaxf(vals[0][2], vals[0][3]));
    float m23 = fmaxf(fmaxf(vals[1][0], vals[1][1]), fmaxf(vals[1][2], vals[1][3]));
    float m45 = fmaxf(fmaxf(vals[2][0], vals[2][1]), fmaxf(vals[2][2], vals[2][3]));
    float m67 = fmaxf(fmaxf(vals[3][0], vals[3][1]), fmaxf(vals[3][2], vals[3][3]));
    float m = fmaxf(fmaxf(m01, m23), fmaxf(m45, m67));
    m = fmaxf(m, __shfl_xor(m, 16));
    m = fmaxf(m, __shfl_xor(m, 32));
    float mn = fmaxf(m_run, m);
    float alpha = __expf(m_run - mn);
    m_run = mn;

    float p[4][4];
    float rs = 0.0f;
#pragma unroll
    for (int j = 0; j < 4; ++j)
#pragma unroll
      for (int r = 0; r < 4; ++r) {
        p[j][r] = __expf(vals[j][r] - mn);
        rs += p[j][r];
      }
    rs += __shfl_xor(rs, 16);
    rs += __shfl_xor(rs, 32);
    l_run = l_run * alpha + rs;

#pragma unroll
    for (int j = 0; j < 4; ++j) {
      bf16 tmp[4] = {__float2bfloat16(p[j][0]), __float2bfloat16(p[j][1]),
                     __float2bfloat16(p[j][2]), __float2bfloat16(p[j][3])};
      int coff = (j * 16 + hig * 4) * 2;
      int byt = q_loc * 128 + (coff ^ ((q_loc & 7) << 4));
      *reinterpret_cast<uint2*>(reinterpret_cast<char*>(&Ps[w][0]) + byt) =
          *reinterpret_cast<const uint2*>(tmp);
    }

#pragma unroll
    for (int r = 0; r < 4; ++r) {
      float alr = __shfl(alpha, hig * 4 + r);
#pragma unroll
      for (int dt = 0; dt < 8; ++dt) o[dt][r] *= alr;
    }

    bf16x8 pa[2];
#pragma unroll
    for (int ks = 0; ks < 2; ++ks) {
      int byt = q_loc * 128 + (((ks * 32 + hig * 8) * 2) ^ ((q_loc & 7) << 4));
      pa[ks] = *reinterpret_cast<const bf16x8*>(reinterpret_cast<const char*>(&Ps[w][0]) + byt);
    }
#pragma unroll
    for (int dt = 0; dt < 8; ++dt)
#pragma unroll
      for (int ks = 0; ks < 2; ++ks) {
        int vrow = dt * 16 + q_loc;
        int byt = vrow * 128 + (((ks * 32 + hig * 8) * 2) ^ ((vrow & 7) << 4));
        bf16x8 vb = *reinterpret_cast<const bf16x8*>(reinterpret_cast<const char*>(Vs) + byt);
        o[dt] = __builtin_amdgcn_mfma_f32_16x16x32_bf16(pa[ks], vb, o[dt], 0, 0, 0);
      }
    __syncthreads();
  }

  if (!split) {
#pragma unroll
    for (int r = 0; r < 4; ++r) {
      float li = __shfl(l_run, hig * 4 + r);
      float linv = 1.0f / li;
#pragma unroll
      for (int dt = 0; dt < 8; ++dt) {
        int qrow = qw + hig * 4 + r;
        int d = dt * 16 + q_loc;
        AO[(size_t)qrow * HID + H * HD + d] = __float2bfloat16(o[dt][r] * linv);
      }
    }
  } else {
    size_t pbase = ((size_t)(half * NH + H) * 1024);
#pragma unroll
    for (int dt = 0; dt < 8; ++dt)
#pragma unroll
      for (int r = 0; r < 4; ++r) {
        int qrow = qw + hig * 4 + r;
        int d = dt * 16 + q_loc;
        Opart[(pbase + (qrow - 1024)) * HD + d] = o[dt][r];
      }
    if (lane < 16) {
      Ml[(pbase + (qa - 1024)) * 2 + 0] = m_run;
      Ml[(pbase + (qa - 1024)) * 2 + 1] = l_run;
    }
  }
}

// ---------------- merge split-attention partials ----------------
__global__ __launch_bounds__(256) void merge_kernel(
    const float* __restrict__ Opart, const float* __restrict__ Ml,
    bf16* __restrict__ AO) {
  int i = blockIdx.x * 256 + threadIdx.x;
  int dq = (i & 31) << 2;
  int row = (i >> 5) & 1023;
  int H = i >> 15;
  size_t b1 = (size_t)H * 1024 + row;
  size_t b2 = (size_t)(NH + H) * 1024 + row;
  float m1 = Ml[b1 * 2], l1 = Ml[b1 * 2 + 1];
  float m2 = Ml[b2 * 2], l2 = Ml[b2 * 2 + 1];
  float M = fmaxf(m1, m2);
  float w1 = __expf(m1 - M), w2 = __expf(m2 - M);
  float inv = 1.0f / (l1 * w1 + l2 * w2);
  float4 o1 = *reinterpret_cast<const float4*>(Opart + b1 * HD + dq);
  float4 o2 = *reinterpret_cast<const float4*>(Opart + b2 * HD + dq);
  bf16 o[4] = {__float2bfloat16((o1.x * w1 + o2.x * w2) * inv),
               __float2bfloat16((o1.y * w1 + o2.y * w2) * inv),
               __float2bfloat16((o1.z * w1 + o2.z * w2) * inv),
               __float2bfloat16((o1.w * w1 + o2.w * w2) * inv)};
  *reinterpret_cast<short4*>(AO + (size_t)(1024 + row) * HID + H * HD + dq) =
      *reinterpret_cast<const short4*>(o);
}

extern "C" void kernel_launch(void* const* d_in, const int* in_sizes, int n_in,
                              void* d_out, int out_size, void* d_ws, size_t ws_size,
                              hipStream_t stream) {
  const float* hidden = (const float*)d_in[0];
  const float* Wq = (const float*)d_in[2];
  const float* bq = (const float*)d_in[3];
  const float* Wk = (const float*)d_in[4];
  const float* bk = (const float*)d_in[5];
  const float* Wv = (const float*)d_in[6];
  const float* bv = (const float*)d_in[7];
  const float* Wo = (const float*)d_in[8];
  float* out = (float*)d_out;

  // workspace map (144 MiB used):
  char* ws = (char*)d_ws;
  bf16*  Wqkvt  = (bf16*)(ws + (size_t)0 * MiB);    // 48 MiB  [Q|K|V]^T bf16
  bf16*  Xb     = (bf16*)(ws + (size_t)48 * MiB);   // 16 MiB
  bf16*  Cqkvh  = (bf16*)(ws + (size_t)64 * MiB);   // 24 MiB  bf16 QKV out [64,88)
  bf16*  Wot    = (bf16*)(ws + (size_t)88 * MiB);   // 32 MiB  [88,120)
  bf16*  Qb     = (bf16*)(ws + (size_t)120 * MiB);  // 16 MiB
  bf16*  Kb     = (bf16*)(ws + (size_t)136 * MiB);  // 4 MiB
  bf16*  Vt     = (bf16*)(ws + (size_t)140 * MiB);  // 4 MiB (ends 144)
  // stream-ordered aliases:
  float* bqkv   = (float*)Qb;                       // consumed by QKV GEMM, then rope overwrites
  bf16*  AO     = Cqkvh;                            // [64,80): Cqkvh dead after postqkv
  float* Opart  = (float*)Wqkvt;                    // [0,32): Wqkvt dead after QKV GEMM
  float* Ml     = (float*)(ws + (size_t)48 * MiB);  // 0.5 MiB inside dead Xb
  float* P0     = (float*)Wqkvt;                    // [0,32): Opart dead after merge
  float* P1     = (float*)(ws + (size_t)16 * MiB);  // [16,48)? NO -> see below
  // P1 must not overlap P0 [0,32): place at [32,64) (Wqkvt tail + Xb, both dead;
  // Ml at 48 is dead after merge, Wo GEMM runs after merge)
  P1 = (float*)(ws + (size_t)32 * MiB);

  cvt_kernel<<<(SEQ * HID) / 1024, 256, 0, stream>>>(hidden, Xb, SEQ * HID);
  concat_bias_kernel<<<QKVN / 256, 256, 0, stream>>>(bq, bk, bv, bqkv);
  transpose_qkvw_kernel<<<24576, dim3(32, 8), 0, stream>>>(Wq, Wk, Wv, Wqkvt);

  // QKV GEMM (192 tiles) + Wo-transpose on the idle 64 blocks
  gemm256_kernel<<<256, 512, 0, stream>>>(
      Xb, Wqkvt, bqkv, nullptr, nullptr, Cqkvh, Wo, Wot, QKVN, HID, HID, 1);

  // fused rope-Q / rope-K / V-transpose
  postqkv_kernel<<<12288, 256, 0, stream>>>(Cqkvh, Qb, Kb, Vt);

  attn_kernel<<<1536, 256, 0, stream>>>(Qb, Kb, Vt, AO, Opart, Ml);
  merge_kernel<<<(NH * 1024 * 32) / 256, 256, 0, stream>>>(Opart, Ml, AO);

  // Wo GEMM (256 blocks, split-K=2) -> P0/P1, then reduce
  gemm256_kernel<<<256, 512, 0, stream>>>(
      AO, Wot, nullptr, P0, P1, nullptr, nullptr, nullptr, HID, 2048, HID, 0);
  reduce_kernel<<<(SEQ * HID) / 1024, 256, 0, stream>>>(P0, P1, out, SEQ * HID);
}